// Round 4
// baseline (1434.178 us; speedup 1.0000x reference)
//
#include <hip/hip_runtime.h>

// MANNet forward, MI355X gfx950.
// Model (validated by rounds 0-3 symptoms): inputs float32, OUTPUT float32.
// All MFMA paths: A-operand compensated bf16 hi+lo, W single-rounded bf16.

#define DEV static __device__ __forceinline__

typedef __attribute__((ext_vector_type(4))) float f32x4;
typedef __attribute__((ext_vector_type(8))) short s16x8;
typedef __attribute__((ext_vector_type(4))) unsigned int u32x4;

constexpr int T = 256, E = 300, EP = 320, H = 128, H2 = 256, H3 = 384, H12 = 1536;
constexpr int M = 1024;            // B*T
constexpr int STY = 262144;        // 4*T*T elements per score type

DEV float b2f(unsigned short h) { return __uint_as_float(((unsigned)h) << 16); }
DEV unsigned short f2b(float f) {
  unsigned u = __float_as_uint(f);
  u += 0x7fff + ((u >> 16) & 1);            // RNE
  return (unsigned short)(u >> 16);
}
DEV float sigm(float x) { return 1.f / (1.f + __expf(-x)); }
DEV float tanh_f(float x) { float e = __expf(2.f * x); return 1.f - 2.f / (e + 1.f); }

DEV s16x8 ldfrag(const unsigned short* p) {
  u32x4 v = *(const u32x4*)p;
  return __builtin_bit_cast(s16x8, v);
}
DEV f32x4 mfma16(s16x8 a, s16x8 b, f32x4 c) {
  return __builtin_amdgcn_mfma_f32_16x16x32_bf16(a, b, c, 0, 0, 0);
}

// ---------------- staging: fp32 -> bf16 (single-rounded) ----------------

struct CvtBatch { const float* s[9]; unsigned short* d[9]; int n[9]; };

__global__ void k_cvt(CvtBatch cb) {
  int seg = blockIdx.y;
  int i = blockIdx.x * 256 + threadIdx.x;
  if (i < cb.n[seg]) cb.d[seg][i] = f2b(cb.s[seg][i]);
}

// embedding gather -> padded hi/lo bf16
__global__ void k_embed(const int* __restrict__ idx, const float* __restrict__ emb,
                        unsigned short* __restrict__ xhi, unsigned short* __restrict__ xlo) {
  int m = blockIdx.x, e = threadIdx.x;                       // 320 threads
  int r = idx[m];
  float v = (e < E) ? emb[(size_t)r * E + e] : 0.f;
  unsigned short hi = f2b(v);
  xhi[(size_t)m * EP + e] = hi;
  xlo[(size_t)m * EP + e] = f2b(v - b2f(hi));
}

// Wih (l,r) fp32 -> bf16, K padded 300->320
__global__ void k_padw(const float* __restrict__ lW, const float* __restrict__ rW,
                       unsigned short* __restrict__ wpad) {
  int i = blockIdx.x * 256 + threadIdx.x;
  if (i >= 4 * H3 * EP) return;
  int e = i % EP, n = (i / EP) % H3, u = i / (EP * H3);
  const float* src = (u < 2 ? lW : rW) + (size_t)((u & 1) * H3 + n) * E;
  wpad[i] = (e < E) ? f2b(src[e]) : (unsigned short)0;
}

// ---------------- generic GEMM: C = (Ahi+Alo) @ W^T (+bias), fp32 out ----------

struct GemmDesc {
  const unsigned short* Ahi; const unsigned short* Alo; const unsigned short* W;
  const float* bias; float* Cf; int N; int K;
};
struct GemmBatch { GemmDesc d[8]; };

__global__ __launch_bounds__(256) void k_gemm(GemmBatch gb) {
  GemmDesc g = gb.d[blockIdx.z];
  int nb = blockIdx.y * 64;
  if (nb >= g.N) return;
  int mb = blockIdx.x * 64;
  int lane = threadIdx.x & 63, w = threadIdx.x >> 6, quad = lane >> 4, l16 = lane & 15;
  int K = g.K;
  const unsigned short* Ahp = g.Ahi + (size_t)(mb + w * 16 + l16) * K + quad * 8;
  const unsigned short* Alp = g.Alo + (size_t)(mb + w * 16 + l16) * K + quad * 8;
  const unsigned short* Wp = g.W + (size_t)(nb + l16) * K + quad * 8;
  f32x4 acc[4];
  #pragma unroll
  for (int nt = 0; nt < 4; ++nt) acc[nt] = f32x4{0.f, 0.f, 0.f, 0.f};
  for (int k = 0; k < K; k += 32) {
    s16x8 ah = ldfrag(Ahp + k);
    s16x8 al = ldfrag(Alp + k);
    #pragma unroll
    for (int nt = 0; nt < 4; ++nt) {
      s16x8 b = ldfrag(Wp + (size_t)nt * 16 * K + k);
      acc[nt] = mfma16(ah, b, acc[nt]);
      acc[nt] = mfma16(al, b, acc[nt]);
    }
  }
  int mr0 = mb + w * 16 + quad * 4;
  #pragma unroll
  for (int nt = 0; nt < 4; ++nt) {
    int col = nb + nt * 16 + l16;
    float bv = g.bias ? g.bias[col] : 0.f;
    #pragma unroll
    for (int r = 0; r < 4; ++r)
      g.Cf[(size_t)(mr0 + r) * g.N + col] = acc[nt][r] + bv;
  }
}

// ---------------- GRU recurrence (one workgroup per direction) ----------------

struct RecArgs {
  const unsigned short* whh[4];   // staged bf16 (384x128)
  const float* pre[4];
  float* outf[4];
  unsigned short* outhi[4];
  unsigned short* outlo[4];
  const float* bhh[4];            // fp32, 384
  int colOff[4];
  int dir[4];
};

__global__ __launch_bounds__(256) void k_gru(RecArgs ra) {
  int u = blockIdx.x;
  __shared__ __align__(16) unsigned short hs_hi[16 * 136];
  __shared__ __align__(16) unsigned short hs_lo[16 * 136];
  __shared__ float h_f[4][128];
  __shared__ float gh[4][H3];
  int tid = threadIdx.x, lane = tid & 63, w = tid >> 6;
  int quad = lane >> 4, l16 = lane & 15;
  for (int i = tid; i < 16 * 136; i += 256) { hs_hi[i] = 0; hs_lo[i] = 0; }
  for (int i = tid; i < 512; i += 256) ((float*)h_f)[i] = 0.f;
  const unsigned short* whh = ra.whh[u];
  s16x8 bq[6][4];
  #pragma unroll
  for (int nt6 = 0; nt6 < 6; ++nt6) {
    int n = (w * 6 + nt6) * 16 + l16;
    #pragma unroll
    for (int kc = 0; kc < 4; ++kc)
      bq[nt6][kc] = ldfrag(whh + (size_t)n * H + kc * 32 + quad * 8);
  }
  const float* bhh = ra.bhh[u];
  const float* pre = ra.pre[u];
  float* outf = ra.outf[u];
  unsigned short* outhi = ra.outhi[u];
  unsigned short* outlo = ra.outlo[u];
  int colOff = ra.colOff[u], dir = ra.dir[u];
  int b0 = tid >> 7, d0 = tid & 127;
  float bh_r = bhh[d0], bh_z = bhh[d0 + 128], bh_n = bhh[d0 + 256];
  __syncthreads();
  for (int s = 0; s < T; ++s) {
    int t = dir ? (T - 1 - s) : s;
    const float* p0 = pre + (size_t)(b0 * T + t) * H3 + d0;
    const float* p1 = pre + (size_t)((b0 + 2) * T + t) * H3 + d0;
    float pr0 = p0[0], pz0 = p0[128], pn0 = p0[256];
    float pr1 = p1[0], pz1 = p1[128], pn1 = p1[256];
    s16x8 ah[4], al[4];
    #pragma unroll
    for (int kc = 0; kc < 4; ++kc) {
      ah[kc] = ldfrag(hs_hi + l16 * 136 + kc * 32 + quad * 8);
      al[kc] = ldfrag(hs_lo + l16 * 136 + kc * 32 + quad * 8);
    }
    #pragma unroll
    for (int nt6 = 0; nt6 < 6; ++nt6) {
      f32x4 a = f32x4{0.f, 0.f, 0.f, 0.f};
      #pragma unroll
      for (int kc = 0; kc < 4; ++kc) a = mfma16(ah[kc], bq[nt6][kc], a);
      #pragma unroll
      for (int kc = 0; kc < 4; ++kc) a = mfma16(al[kc], bq[nt6][kc], a);
      if (quad == 0) {                       // D rows 0..3 = batches
        int col = (w * 6 + nt6) * 16 + l16;
        #pragma unroll
        for (int r = 0; r < 4; ++r) gh[r][col] = a[r];
      }
    }
    __syncthreads();
    #pragma unroll
    for (int p = 0; p < 2; ++p) {
      int b = b0 + p * 2;
      float pr = p ? pr1 : pr0, pz = p ? pz1 : pz0, pn = p ? pn1 : pn0;
      float gr = gh[b][d0] + bh_r;
      float gz = gh[b][d0 + 128] + bh_z;
      float gn = gh[b][d0 + 256] + bh_n;
      float rg = sigm(pr + gr), zg = sigm(pz + gz);
      float ng = tanh_f(pn + rg * gn);
      float hn = (1.f - zg) * ng + zg * h_f[b][d0];
      h_f[b][d0] = hn;
      unsigned short hi = f2b(hn);
      unsigned short lo = f2b(hn - b2f(hi));
      hs_hi[b * 136 + d0] = hi;
      hs_lo[b * 136 + d0] = lo;
      size_t o = (size_t)(b * T + t) * H2 + colOff + d0;
      outf[o] = hn;
      outhi[o] = hi;
      outlo[o] = lo;
    }
    __syncthreads();
  }
}

// ---------------- cheap scores: co-attention (c), bilinear (b), subtractive (m) ----

__global__ __launch_bounds__(256) void k_score_cmb(
    const float* __restrict__ Hc, const float* __restrict__ Rc,
    const float* __restrict__ Hm, const float* __restrict__ Rm,
    const float* __restrict__ HB, const float* __restrict__ hrf,
    const float* __restrict__ vcf, const float* __restrict__ vmf,
    float* __restrict__ S) {
  int bi = blockIdx.x, b = bi >> 8;
  __shared__ __align__(16) float rc_l[128];
  __shared__ __align__(16) float rm_l[128];
  __shared__ __align__(16) float vc_l[128];
  __shared__ __align__(16) float vm_l[128];
  __shared__ __align__(16) float hr_l[256];
  int tid = threadIdx.x;
  if (tid < 128) {
    rc_l[tid] = Rc[(size_t)bi * 128 + tid];
    rm_l[tid] = Rm[(size_t)bi * 128 + tid];
    vc_l[tid] = vcf[tid];
    vm_l[tid] = vmf[tid];
  }
  hr_l[tid] = hrf[(size_t)bi * 256 + tid];
  __syncthreads();
  int j = tid;
  const float4* hc4 = (const float4*)(Hc + (size_t)(b * 256 + j) * 128);
  const float4* hm4 = (const float4*)(Hm + (size_t)(b * 256 + j) * 128);
  const float4* hb4 = (const float4*)(HB + (size_t)(b * 256 + j) * 256);
  const float4* rc4 = (const float4*)rc_l;
  const float4* rm4 = (const float4*)rm_l;
  const float4* vc4 = (const float4*)vc_l;
  const float4* vm4 = (const float4*)vm_l;
  const float4* hr4 = (const float4*)hr_l;
  float sc = 0.f, sm = 0.f, sb = 0.f;
  #pragma unroll 4
  for (int k = 0; k < 32; ++k) {
    float4 a = hc4[k], c = rc4[k], v = vc4[k];
    sc += v.x * tanh_f(a.x + c.x) + v.y * tanh_f(a.y + c.y)
        + v.z * tanh_f(a.z + c.z) + v.w * tanh_f(a.w + c.w);
    float4 am = hm4[k], cm = rm4[k], vv = vm4[k];
    sm += vv.x * tanh_f(am.x - cm.x) + vv.y * tanh_f(am.y - cm.y)
        + vv.z * tanh_f(am.z - cm.z) + vv.w * tanh_f(am.w - cm.w);
  }
  #pragma unroll 4
  for (int k = 0; k < 64; ++k) {
    float4 p = hb4[k], h = hr4[k];
    sb += p.x * h.x + p.y * h.y + p.z * h.z + p.w * h.w;
  }
  size_t o = (size_t)bi * 256 + j;
  S[(size_t)STY * 1 + o] = sc;   // c
  S[(size_t)STY * 3 + o] = sb;   // b
  S[(size_t)STY * 4 + o] = sm;   // m
}

// ---------------- expensive scores: S[i,j] = v . tanh(W (X_j o R_i)) ------------

__global__ __launch_bounds__(256) void k_score_ds(
    const unsigned short* __restrict__ Xhi, const unsigned short* __restrict__ Xlo,
    const float* __restrict__ Rf, const float* __restrict__ W,
    const float* __restrict__ v, float* __restrict__ Sout) {
  int bi = blockIdx.x, b = bi >> 8;
  __shared__ __align__(16) unsigned short w_lds[64 * 264];
  __shared__ float hr_l[256];
  __shared__ float sp[4][256];
  int tid = threadIdx.x, lane = tid & 63, w = tid >> 6, quad = lane >> 4, l16 = lane & 15;
  hr_l[tid] = Rf[(size_t)bi * 256 + tid];
  #pragma unroll
  for (int ww = 0; ww < 4; ++ww) sp[ww][tid] = 0.f;
  __syncthreads();
  for (int p = 0; p < 2; ++p) {
    for (int idx = tid; idx < 64 * 256; idx += 256) {
      int kl = idx >> 8, d = idx & 255;
      w_lds[kl * 264 + d] = f2b(W[(size_t)(p * 64 + kl) * 256 + d] * hr_l[d]);
    }
    __syncthreads();
    int kcol = w * 16 + l16;
    float vv = v[p * 64 + kcol];
    s16x8 bfr[8];
    #pragma unroll
    for (int kc = 0; kc < 8; ++kc)
      bfr[kc] = ldfrag(w_lds + kcol * 264 + kc * 32 + quad * 8);
    for (int jt = 0; jt < 16; ++jt) {
      size_t rowoff = (size_t)(b * 256 + jt * 16 + l16) * 256 + quad * 8;
      f32x4 acc = f32x4{0.f, 0.f, 0.f, 0.f};
      #pragma unroll
      for (int kc = 0; kc < 8; ++kc) {
        acc = mfma16(ldfrag(Xhi + rowoff + kc * 32), bfr[kc], acc);
        acc = mfma16(ldfrag(Xlo + rowoff + kc * 32), bfr[kc], acc);
      }
      #pragma unroll
      for (int r = 0; r < 4; ++r) {
        float t = tanh_f(acc[r]) * vv;
        t += __shfl_xor(t, 1); t += __shfl_xor(t, 2);
        t += __shfl_xor(t, 4); t += __shfl_xor(t, 8);
        if (l16 == 0) sp[w][jt * 16 + quad * 4 + r] += t;
      }
    }
    __syncthreads();
  }
  Sout[(size_t)bi * 256 + tid] = sp[0][tid] + sp[1][tid] + sp[2][tid] + sp[3][tid];
}

// ---------------- softmax over j for all 5 score types (fp32 out) --------------

__global__ __launch_bounds__(256) void k_softmax(const float* __restrict__ S,
                                                 float* __restrict__ P) {
  int bi = blockIdx.x, tid = threadIdx.x;
  __shared__ float red[4];
  for (int type = 0; type < 5; ++type) {
    size_t o = (size_t)type * STY + (size_t)bi * 256 + tid;
    float x = S[o];
    float m = x;
    for (int d = 32; d; d >>= 1) m = fmaxf(m, __shfl_xor(m, d));
    if ((tid & 63) == 0) red[tid >> 6] = m;
    __syncthreads();
    m = fmaxf(fmaxf(red[0], red[1]), fmaxf(red[2], red[3]));
    __syncthreads();
    float e = __expf(x - m);
    float sum = e;
    for (int d = 32; d; d >>= 1) sum += __shfl_xor(sum, d);
    if ((tid & 63) == 0) red[tid >> 6] = sum;
    __syncthreads();
    sum = red[0] + red[1] + red[2] + red[3];
    P[o] = e / sum;
    __syncthreads();
  }
}

// ---------------- agg assembly: hr copy + 5 weighted sums (hi/lo bf16 out) ------

__global__ void k_aggcopy(const float* __restrict__ hr_f,
                          unsigned short* __restrict__ ahi, unsigned short* __restrict__ alo) {
  int m = blockIdx.x, d = threadIdx.x;
  float v = hr_f[(size_t)m * H2 + d];
  unsigned short hi = f2b(v);
  ahi[(size_t)m * H12 + d] = hi;
  alo[(size_t)m * H12 + d] = f2b(v - b2f(hi));
}

__global__ __launch_bounds__(256) void k_wsum(const float* __restrict__ P,
    const float* __restrict__ hl_f, const float* __restrict__ hr_f,
    unsigned short* __restrict__ ahi, unsigned short* __restrict__ alo) {
  int it = blockIdx.x, type = blockIdx.y, b = blockIdx.z;
  __shared__ float p_l[8][256];
  int tid = threadIdx.x;
  for (int ii = 0; ii < 8; ++ii)
    p_l[ii][tid] = P[((size_t)(type * 4 + b) * 256 + it * 8 + ii) * 256 + tid];
  __syncthreads();
  const float* src = (type == 0 ? hr_f : hl_f) + (size_t)b * 256 * 256;
  float acc[8] = {0.f, 0.f, 0.f, 0.f, 0.f, 0.f, 0.f, 0.f};
  for (int j = 0; j < 256; ++j) {
    float hv = src[(size_t)j * 256 + tid];
    #pragma unroll
    for (int ii = 0; ii < 8; ++ii) acc[ii] += p_l[ii][j] * hv;
  }
  int off = 256 * (1 + type);      // agg: [hr | pts | ptc | ptd | ptb | ptm]
  #pragma unroll
  for (int ii = 0; ii < 8; ++ii) {
    float vv = acc[ii];
    unsigned short hi = f2b(vv);
    size_t o = (size_t)(b * 256 + it * 8 + ii) * H12 + off + tid;
    ahi[o] = hi;
    alo[o] = f2b(vv - b2f(hi));
  }
}

// ---------------- pooling over hl -> rl, Rlc = rl @ Wc2^T ----------------

__global__ __launch_bounds__(256) void k_pool(const float* __restrict__ Hp,
    const float* __restrict__ hl_f, const float* __restrict__ vpf,
    const float* __restrict__ Wc2f, float* __restrict__ Rlc) {
  int b = blockIdx.x, tid = threadIdx.x;
  __shared__ float vpl[128], wl[256], rll[256], red[4];
  if (tid < 128) vpl[tid] = vpf[tid];
  __syncthreads();
  const float* hp = Hp + (size_t)(b * 256 + tid) * 128;
  float s = 0.f;
  for (int k = 0; k < 128; ++k) s += vpl[k] * tanh_f(hp[k]);
  float m = s;
  for (int d = 32; d; d >>= 1) m = fmaxf(m, __shfl_xor(m, d));
  if ((tid & 63) == 0) red[tid >> 6] = m;
  __syncthreads();
  m = fmaxf(fmaxf(red[0], red[1]), fmaxf(red[2], red[3]));
  __syncthreads();
  float e = __expf(s - m);
  float sum = e;
  for (int d = 32; d; d >>= 1) sum += __shfl_xor(sum, d);
  if ((tid & 63) == 0) red[tid >> 6] = sum;
  __syncthreads();
  sum = red[0] + red[1] + red[2] + red[3];
  wl[tid] = e / sum;
  __syncthreads();
  float acc = 0.f;
  for (int t = 0; t < 256; ++t) acc += wl[t] * hl_f[(size_t)(b * 256 + t) * 256 + tid];
  rll[tid] = acc;
  __syncthreads();
  if (tid < 128) {
    float a2 = 0.f;
    const float* wr = Wc2f + (size_t)tid * 256;
    for (int d = 0; d < 256; ++d) a2 += rll[d] * wr[d];
    Rlc[b * 128 + tid] = a2;
  }
}

// ---------------- final attention over ar + prediction (fp32 out) --------------

__global__ __launch_bounds__(256) void k_final(const float* __restrict__ Arc,
    const float* __restrict__ ar_f, const float* __restrict__ Rlc,
    const float* __restrict__ vcf, const float* __restrict__ Wpredf,
    float* __restrict__ out) {
  int b = blockIdx.x, tid = threadIdx.x;
  __shared__ float vcl[128], rlcl[128], wl[256], rrl[256], red[4];
  if (tid < 128) { vcl[tid] = vcf[tid]; rlcl[tid] = Rlc[b * 128 + tid]; }
  __syncthreads();
  const float* ap = Arc + (size_t)(b * 256 + tid) * 128;
  float s = 0.f;
  for (int k = 0; k < 128; ++k) s += vcl[k] * (ap[k] + rlcl[k]);   // no tanh here
  float m = s;
  for (int d = 32; d; d >>= 1) m = fmaxf(m, __shfl_xor(m, d));
  if ((tid & 63) == 0) red[tid >> 6] = m;
  __syncthreads();
  m = fmaxf(fmaxf(red[0], red[1]), fmaxf(red[2], red[3]));
  __syncthreads();
  float e = __expf(s - m);
  float sum = e;
  for (int d = 32; d; d >>= 1) sum += __shfl_xor(sum, d);
  if ((tid & 63) == 0) red[tid >> 6] = sum;
  __syncthreads();
  sum = red[0] + red[1] + red[2] + red[3];
  wl[tid] = e / sum;
  __syncthreads();
  float acc = 0.f;
  for (int t = 0; t < 256; ++t) acc += wl[t] * ar_f[(size_t)(b * 256 + t) * 256 + tid];
  rrl[tid] = acc;
  __syncthreads();
  if (tid < 2) {
    float o = 0.f;
    const float* wp = Wpredf + (size_t)tid * 256;
    for (int d = 0; d < 256; ++d) o += rrl[d] * wp[d];
    out[b * 2 + tid] = sigm(o);            // FLOAT32 output
  }
}

// ---------------- host ----------------

extern "C" void kernel_launch(void* const* d_in, const int* in_sizes, int n_in,
                              void* d_out, int out_size, void* d_ws, size_t ws_size,
                              hipStream_t stream) {
  (void)in_sizes; (void)n_in; (void)out_size;
  const int* inputs = (const int*)d_in[0];
  const float* embed = (const float*)d_in[1];
  const float* lWih = (const float*)d_in[2];
  const float* lWhh = (const float*)d_in[3];
  const float* lbih = (const float*)d_in[4];
  const float* lbhh = (const float*)d_in[5];
  const float* rWih = (const float*)d_in[6];
  const float* rWhh = (const float*)d_in[7];
  const float* rbih = (const float*)d_in[8];
  const float* rbhh = (const float*)d_in[9];
  const float* aWih = (const float*)d_in[10];
  const float* aWhh = (const float*)d_in[11];
  const float* abih = (const float*)d_in[12];
  const float* abhh = (const float*)d_in[13];
  const float* Wc1 = (const float*)d_in[14];
  const float* Wc2 = (const float*)d_in[15];
  const float* vc  = (const float*)d_in[16];
  const float* Wb  = (const float*)d_in[17];
  const float* Wd  = (const float*)d_in[18];
  const float* vd  = (const float*)d_in[19];
  const float* Wm  = (const float*)d_in[20];
  const float* vmv = (const float*)d_in[21];
  const float* Wsw = (const float*)d_in[22];
  const float* vsv = (const float*)d_in[23];
  const float* Wp  = (const float*)d_in[24];
  const float* vp  = (const float*)d_in[25];
  const float* Wpred = (const float*)d_in[26];

  char* ws = (char*)d_ws;
  size_t off = 0;
  auto alloc = [&](size_t bytes) -> void* {
    void* p = ws + off;
    off += (bytes + 255) & ~(size_t)255;
    return p;
  };
  unsigned short* xhi = (unsigned short*)alloc((size_t)M * EP * 2);
  unsigned short* xlo = (unsigned short*)alloc((size_t)M * EP * 2);
  unsigned short* wpad = (unsigned short*)alloc((size_t)4 * H3 * EP * 2);
  unsigned short* Whh_b = (unsigned short*)alloc((size_t)6 * H3 * H * 2);
  unsigned short* aWih_b = (unsigned short*)alloc((size_t)2 * H3 * H12 * 2);
  unsigned short* Wc1_b = (unsigned short*)alloc((size_t)H * H2 * 2);
  unsigned short* Wc2_b = (unsigned short*)alloc((size_t)H * H2 * 2);
  unsigned short* Wm_b  = (unsigned short*)alloc((size_t)H * H2 * 2);
  unsigned short* Wp_b  = (unsigned short*)alloc((size_t)H * H2 * 2);
  unsigned short* Wb_b  = (unsigned short*)alloc((size_t)H2 * H2 * 2);
  // region1 (6.29 MB) hosts pre_lr -> S -> pre_a (strictly sequential lifetimes)
  char* region1 = (char*)alloc((size_t)4 * M * H3 * 4);
  float* pre_lr = (float*)region1;
  float* S      = (float*)region1;
  float* pre_a  = (float*)region1;
  float* hl_f = (float*)alloc((size_t)M * H2 * 4);
  float* hr_f = (float*)alloc((size_t)M * H2 * 4);
  unsigned short* hl_hi = (unsigned short*)alloc((size_t)M * H2 * 2);
  unsigned short* hl_lo = (unsigned short*)alloc((size_t)M * H2 * 2);
  unsigned short* hr_hi = (unsigned short*)alloc((size_t)M * H2 * 2);
  unsigned short* hr_lo = (unsigned short*)alloc((size_t)M * H2 * 2);
  float* Hc = (float*)alloc((size_t)M * H * 4);
  float* Rc = (float*)alloc((size_t)M * H * 4);
  float* Hm = (float*)alloc((size_t)M * H * 4);
  float* Rm = (float*)alloc((size_t)M * H * 4);
  float* Hp = (float*)alloc((size_t)M * H * 4);
  float* HB = (float*)alloc((size_t)M * H2 * 4);
  float* P = (float*)alloc((size_t)5 * STY * 4);
  unsigned short* agg_hi = (unsigned short*)alloc((size_t)M * H12 * 2);
  unsigned short* agg_lo = (unsigned short*)alloc((size_t)M * H12 * 2);
  float* ar_f = (float*)alloc((size_t)M * H2 * 4);
  unsigned short* ar_hi = (unsigned short*)alloc((size_t)M * H2 * 2);
  unsigned short* ar_lo = (unsigned short*)alloc((size_t)M * H2 * 2);
  float* Arc = (float*)alloc((size_t)M * H * 4);
  float* Rlc = (float*)alloc(4 * H * 4);

  // Safety: clear used workspace (cheap; removes any coverage-hole doubt).
  size_t used = off < ws_size ? off : ws_size;
  hipMemsetAsync(d_ws, 0, used, stream);

  // stage bf16 weights
  CvtBatch cb{};
  cb.s[0] = lWhh;  cb.d[0] = Whh_b;                 cb.n[0] = 2 * H3 * H;
  cb.s[1] = rWhh;  cb.d[1] = Whh_b + 2 * H3 * H;    cb.n[1] = 2 * H3 * H;
  cb.s[2] = aWhh;  cb.d[2] = Whh_b + 4 * H3 * H;    cb.n[2] = 2 * H3 * H;
  cb.s[3] = aWih;  cb.d[3] = aWih_b;                cb.n[3] = 2 * H3 * H12;
  cb.s[4] = Wc1;   cb.d[4] = Wc1_b;                 cb.n[4] = H * H2;
  cb.s[5] = Wc2;   cb.d[5] = Wc2_b;                 cb.n[5] = H * H2;
  cb.s[6] = Wm;    cb.d[6] = Wm_b;                  cb.n[6] = H * H2;
  cb.s[7] = Wp;    cb.d[7] = Wp_b;                  cb.n[7] = H * H2;
  cb.s[8] = Wb;    cb.d[8] = Wb_b;                  cb.n[8] = H2 * H2;
  k_cvt<<<dim3((2 * H3 * H12 + 255) / 256, 9), dim3(256), 0, stream>>>(cb);

  k_embed<<<dim3(M), dim3(EP), 0, stream>>>(inputs, embed, xhi, xlo);
  k_padw<<<dim3((4 * H3 * EP + 255) / 256), dim3(256), 0, stream>>>(lWih, rWih, wpad);

  GemmBatch ga{};
  const float* biases[4] = { lbih, lbih + H3, rbih, rbih + H3 };
  for (int u = 0; u < 4; ++u)
    ga.d[u] = GemmDesc{ xhi, xlo, wpad + (size_t)u * H3 * EP, biases[u],
                        pre_lr + (size_t)u * M * H3, H3, EP };
  k_gemm<<<dim3(16, 6, 4), dim3(256), 0, stream>>>(ga);

  RecArgs r1{};
  r1.whh[0] = Whh_b;               r1.whh[1] = Whh_b + H3 * H;
  r1.whh[2] = Whh_b + 2 * H3 * H;  r1.whh[3] = Whh_b + 3 * H3 * H;
  for (int u = 0; u < 4; ++u) r1.pre[u] = pre_lr + (size_t)u * M * H3;
  r1.outf[0] = r1.outf[1] = hl_f; r1.outf[2] = r1.outf[3] = hr_f;
  r1.outhi[0] = r1.outhi[1] = hl_hi; r1.outhi[2] = r1.outhi[3] = hr_hi;
  r1.outlo[0] = r1.outlo[1] = hl_lo; r1.outlo[2] = r1.outlo[3] = hr_lo;
  r1.bhh[0] = lbhh; r1.bhh[1] = lbhh + H3; r1.bhh[2] = rbhh; r1.bhh[3] = rbhh + H3;
  r1.colOff[0] = 0; r1.colOff[1] = H; r1.colOff[2] = 0; r1.colOff[3] = H;
  r1.dir[0] = 0; r1.dir[1] = 1; r1.dir[2] = 0; r1.dir[3] = 1;
  k_gru<<<dim3(4), dim3(256), 0, stream>>>(r1);

  GemmBatch gbB{};
  gbB.d[0] = GemmDesc{ hl_hi, hl_lo, Wc1_b, nullptr, Hc, H, H2 };
  gbB.d[1] = GemmDesc{ hr_hi, hr_lo, Wc2_b, nullptr, Rc, H, H2 };
  gbB.d[2] = GemmDesc{ hl_hi, hl_lo, Wm_b, nullptr, Hm, H, H2 };
  gbB.d[3] = GemmDesc{ hr_hi, hr_lo, Wm_b, nullptr, Rm, H, H2 };
  gbB.d[4] = GemmDesc{ hl_hi, hl_lo, Wb_b, nullptr, HB, H2, H2 };
  gbB.d[5] = GemmDesc{ hl_hi, hl_lo, Wp_b, nullptr, Hp, H, H2 };
  k_gemm<<<dim3(16, 4, 6), dim3(256), 0, stream>>>(gbB);

  k_score_cmb<<<dim3(M), dim3(256), 0, stream>>>(Hc, Rc, Hm, Rm, HB, hr_f, vc, vmv, S);
  k_score_ds<<<dim3(M), dim3(256), 0, stream>>>(hl_hi, hl_lo, hr_f, Wd, vd,
                                                S + (size_t)2 * STY);
  k_score_ds<<<dim3(M), dim3(256), 0, stream>>>(hr_hi, hr_lo, hr_f, Wsw, vsv,
                                                S + (size_t)0 * STY);
  k_softmax<<<dim3(M), dim3(256), 0, stream>>>(S, P);
  k_aggcopy<<<dim3(M), dim3(256), 0, stream>>>(hr_f, agg_hi, agg_lo);
  k_wsum<<<dim3(32, 5, 4), dim3(256), 0, stream>>>(P, hl_f, hr_f, agg_hi, agg_lo);

  GemmBatch gc{};
  gc.d[0] = GemmDesc{ agg_hi, agg_lo, aWih_b, abih, pre_a, H3, H12 };
  gc.d[1] = GemmDesc{ agg_hi, agg_lo, aWih_b + (size_t)H3 * H12, abih + H3,
                      pre_a + (size_t)M * H3, H3, H12 };
  k_gemm<<<dim3(16, 6, 2), dim3(256), 0, stream>>>(gc);

  RecArgs r2{};
  r2.whh[0] = Whh_b + 4 * H3 * H; r2.whh[1] = Whh_b + 5 * H3 * H;
  r2.whh[2] = r2.whh[3] = Whh_b + 4 * H3 * H;
  r2.pre[0] = pre_a; r2.pre[1] = pre_a + (size_t)M * H3;
  r2.pre[2] = r2.pre[3] = pre_a;
  r2.outf[0] = r2.outf[1] = r2.outf[2] = r2.outf[3] = ar_f;
  r2.outhi[0] = r2.outhi[1] = r2.outhi[2] = r2.outhi[3] = ar_hi;
  r2.outlo[0] = r2.outlo[1] = r2.outlo[2] = r2.outlo[3] = ar_lo;
  r2.bhh[0] = abhh; r2.bhh[1] = abhh + H3; r2.bhh[2] = r2.bhh[3] = abhh;
  r2.colOff[0] = 0; r2.colOff[1] = H; r2.colOff[2] = r2.colOff[3] = 0;
  r2.dir[0] = 0; r2.dir[1] = 1; r2.dir[2] = r2.dir[3] = 0;
  k_gru<<<dim3(2), dim3(256), 0, stream>>>(r2);

  GemmBatch gd{};
  gd.d[0] = GemmDesc{ ar_hi, ar_lo, Wc1_b, nullptr, Arc, H, H2 };
  k_gemm<<<dim3(16, 2, 1), dim3(256), 0, stream>>>(gd);

  k_pool<<<dim3(4), dim3(256), 0, stream>>>(Hp, hl_f, vp, Wc2, Rlc);
  k_final<<<dim3(4), dim3(256), 0, stream>>>(Arc, ar_f, Rlc, vc, Wpred,
                                             (float*)d_out);
}

// Round 5
// 1263.203 us; speedup vs baseline: 1.1353x; 1.1353x over previous
//
#include <hip/hip_runtime.h>

// MANNet forward, MI355X gfx950. Inputs fp32 (+int32 ids), output fp32.
// MFMA paths: A compensated bf16 hi+lo, W single-rounded bf16.
// R5: k_gru rewritten — 1 barrier/step (ping-pong h, wave-local gh via column
// permutation), pre prefetch, hi/lo-as-A-rows (halves MFMA), batched out stores.

#define DEV static __device__ __forceinline__

typedef __attribute__((ext_vector_type(4))) float f32x4;
typedef __attribute__((ext_vector_type(8))) short s16x8;
typedef __attribute__((ext_vector_type(4))) unsigned int u32x4;

constexpr int T = 256, E = 300, EP = 320, H = 128, H2 = 256, H3 = 384, H12 = 1536;
constexpr int M = 1024;            // B*T
constexpr int STY = 262144;        // 4*T*T elements per score type

DEV float b2f(unsigned short h) { return __uint_as_float(((unsigned)h) << 16); }
DEV unsigned short f2b(float f) {
  unsigned u = __float_as_uint(f);
  u += 0x7fff + ((u >> 16) & 1);            // RNE
  return (unsigned short)(u >> 16);
}
DEV float sigm(float x) { return 1.f / (1.f + __expf(-x)); }
DEV float tanh_f(float x) { float e = __expf(2.f * x); return 1.f - 2.f / (e + 1.f); }

DEV s16x8 ldfrag(const unsigned short* p) {
  u32x4 v = *(const u32x4*)p;
  return __builtin_bit_cast(s16x8, v);
}
DEV f32x4 mfma16(s16x8 a, s16x8 b, f32x4 c) {
  return __builtin_amdgcn_mfma_f32_16x16x32_bf16(a, b, c, 0, 0, 0);
}

// ---------------- fused staging: 9x cvt + embed + padw ----------------

struct StageArgs {
  const float* cs[9]; unsigned short* cd[9]; int cn[9];
  const int* idx; const float* emb; unsigned short* xhi; unsigned short* xlo;
  const float* lW; const float* rW; unsigned short* wpad;
};

__global__ void k_stage(StageArgs sa) {
  int seg = blockIdx.y;
  int i = blockIdx.x * 256 + threadIdx.x;
  if (seg < 9) {
    if (i < sa.cn[seg]) sa.cd[seg][i] = f2b(sa.cs[seg][i]);
    return;
  }
  if (seg == 9) {                       // embedding gather -> padded hi/lo
    if (i >= M * EP) return;
    int m = i / EP, e = i - m * EP;
    int r = sa.idx[m];
    float v = (e < E) ? sa.emb[(size_t)r * E + e] : 0.f;
    unsigned short hi = f2b(v);
    sa.xhi[i] = hi;
    sa.xlo[i] = f2b(v - b2f(hi));
    return;
  }
  // seg 10: Wih (l,r) -> bf16, K padded 300->320
  if (i >= 4 * H3 * EP) return;
  int e = i % EP, n = (i / EP) % H3, uu = i / (EP * H3);
  const float* src = (uu < 2 ? sa.lW : sa.rW) + (size_t)((uu & 1) * H3 + n) * E;
  sa.wpad[i] = (e < E) ? f2b(src[e]) : (unsigned short)0;
}

// ---------------- generic GEMM: C = (Ahi+Alo) @ W^T (+bias), fp32 out ----------

struct GemmDesc {
  const unsigned short* Ahi; const unsigned short* Alo; const unsigned short* W;
  const float* bias; float* Cf; int N; int K;
};
struct GemmBatch { GemmDesc d[8]; };

__global__ __launch_bounds__(256) void k_gemm(GemmBatch gb) {
  GemmDesc g = gb.d[blockIdx.z];
  int nb = blockIdx.y * 64;
  if (nb >= g.N) return;
  int mb = blockIdx.x * 64;
  int lane = threadIdx.x & 63, w = threadIdx.x >> 6, quad = lane >> 4, l16 = lane & 15;
  int K = g.K;
  const unsigned short* Ahp = g.Ahi + (size_t)(mb + w * 16 + l16) * K + quad * 8;
  const unsigned short* Alp = g.Alo + (size_t)(mb + w * 16 + l16) * K + quad * 8;
  const unsigned short* Wp = g.W + (size_t)(nb + l16) * K + quad * 8;
  f32x4 acc[4];
  #pragma unroll
  for (int nt = 0; nt < 4; ++nt) acc[nt] = f32x4{0.f, 0.f, 0.f, 0.f};
  for (int k = 0; k < K; k += 32) {
    s16x8 ah = ldfrag(Ahp + k);
    s16x8 al = ldfrag(Alp + k);
    #pragma unroll
    for (int nt = 0; nt < 4; ++nt) {
      s16x8 b = ldfrag(Wp + (size_t)nt * 16 * K + k);
      acc[nt] = mfma16(ah, b, acc[nt]);
      acc[nt] = mfma16(al, b, acc[nt]);
    }
  }
  int mr0 = mb + w * 16 + quad * 4;
  #pragma unroll
  for (int nt = 0; nt < 4; ++nt) {
    int col = nb + nt * 16 + l16;
    float bv = g.bias ? g.bias[col] : 0.f;
    #pragma unroll
    for (int r = 0; r < 4; ++r)
      g.Cf[(size_t)(mr0 + r) * g.N + col] = acc[nt][r] + bv;
  }
}

// ---------------- GRU recurrence: 1 barrier/step ----------------
// Column permutation: wave w owns gate dims d in [w*32,(w+1)*32). Its 6 MFMA
// tiles are r[d:+16],r[+16:+32],z[...],z[...],n[...],n[...] so gate math is
// wave-local. A rows 0-3 = h_hi (batches), rows 4-7 = h_lo, 8-15 zero; one
// MFMA covers hi+lo (summed in fp32 at the gate). h state ping-pongs between
// two LDS buffers so a single end-of-step barrier suffices.

struct RecArgs {
  const unsigned short* whh[4];   // staged bf16 (384x128)
  const float* pre[4];
  float* outf[4];
  const float* bhh[4];            // fp32, 384
  int colOff[4];
  int dir[4];
};

__global__ __launch_bounds__(256) void k_gru(RecArgs ra) {
  int u = blockIdx.x;
  __shared__ __align__(16) unsigned short hs[2][16 * 136];
  __shared__ float gh_l[4 * 8 * 96];
  int tid = threadIdx.x, lane = tid & 63, w = tid >> 6;
  int quad = lane >> 4, l16 = lane & 15;
  for (int i = tid; i < 2 * 16 * 136; i += 256) ((unsigned short*)hs)[i] = 0;
  const unsigned short* whh = ra.whh[u];
  s16x8 bq[6][4];
  #pragma unroll
  for (int nt = 0; nt < 6; ++nt) {
    int row = (nt >> 1) * 128 + w * 32 + (nt & 1) * 16 + l16;
    #pragma unroll
    for (int kc = 0; kc < 4; ++kc)
      bq[nt][kc] = ldfrag(whh + (size_t)row * H + kc * 32 + quad * 8);
  }
  const float* bhh = ra.bhh[u];
  const float* pre = ra.pre[u];
  float* outf = ra.outf[u];
  int colOff = ra.colOff[u], dir = ra.dir[u];
  int dd = lane & 31, bp = lane >> 5, b2 = bp + 2;
  int d = w * 32 + dd;
  float bh_r = bhh[d], bh_z = bhh[d + 128], bh_n = bhh[d + 256];
  float hf0 = 0.f, hf1 = 0.f;
  float ob0[8], ob1[8];
  int ghw = w * 8;
  // prefetch step 0
  int t0 = dir ? (T - 1) : 0;
  {
    const float* q0 = pre + (size_t)(bp * T + t0) * H3 + d;
    const float* q1 = pre + (size_t)(b2 * T + t0) * H3 + d;
    ob0[0] = q0[0]; ob0[1] = q0[128]; ob0[2] = q0[256];
    ob1[0] = q1[0]; ob1[1] = q1[128]; ob1[2] = q1[256];
  }
  float n_pr0 = ob0[0], n_pz0 = ob0[1], n_pn0 = ob0[2];
  float n_pr1 = ob1[0], n_pz1 = ob1[1], n_pn1 = ob1[2];
  __syncthreads();
  for (int sb = 0; sb < T; sb += 8) {
    #pragma unroll
    for (int ss = 0; ss < 8; ++ss) {
      int s = sb + ss;
      float pr0 = n_pr0, pz0 = n_pz0, pn0 = n_pn0;
      float pr1 = n_pr1, pz1 = n_pz1, pn1 = n_pn1;
      // issue next-step pre loads (consumed next iteration)
      int sn = (s + 1 < T) ? (s + 1) : s;
      int tn = dir ? (T - 1 - sn) : sn;
      const float* f0 = pre + (size_t)(bp * T + tn) * H3 + d;
      const float* f1 = pre + (size_t)(b2 * T + tn) * H3 + d;
      n_pr0 = f0[0]; n_pz0 = f0[128]; n_pn0 = f0[256];
      n_pr1 = f1[0]; n_pz1 = f1[128]; n_pn1 = f1[256];
      const unsigned short* hcur = hs[ss & 1];
      unsigned short* hnxt = hs[(ss & 1) ^ 1];
      s16x8 ah[4];
      #pragma unroll
      for (int kc = 0; kc < 4; ++kc)
        ah[kc] = ldfrag(hcur + l16 * 136 + kc * 32 + quad * 8);
      f32x4 acc[6];
      #pragma unroll
      for (int nt = 0; nt < 6; ++nt) acc[nt] = f32x4{0.f, 0.f, 0.f, 0.f};
      #pragma unroll
      for (int kc = 0; kc < 4; ++kc) {
        #pragma unroll
        for (int nt = 0; nt < 6; ++nt)
          acc[nt] = mfma16(ah[kc], bq[nt][kc], acc[nt]);
      }
      if (quad < 2) {                       // quad0: hi rows 0-3; quad1: lo rows 4-7
        #pragma unroll
        for (int nt = 0; nt < 6; ++nt) {
          int gcol = (nt >> 1) * 32 + (nt & 1) * 16 + l16;
          #pragma unroll
          for (int r = 0; r < 4; ++r)
            gh_l[(ghw + quad * 4 + r) * 96 + gcol] = acc[nt][r];
        }
      }
      __asm__ volatile("s_waitcnt lgkmcnt(0)" ::: "memory");
      float r0 = gh_l[(ghw + bp) * 96 + dd]      + gh_l[(ghw + 4 + bp) * 96 + dd];
      float z0 = gh_l[(ghw + bp) * 96 + 32 + dd] + gh_l[(ghw + 4 + bp) * 96 + 32 + dd];
      float nv0 = gh_l[(ghw + bp) * 96 + 64 + dd] + gh_l[(ghw + 4 + bp) * 96 + 64 + dd];
      float r1 = gh_l[(ghw + b2) * 96 + dd]      + gh_l[(ghw + 4 + b2) * 96 + dd];
      float z1 = gh_l[(ghw + b2) * 96 + 32 + dd] + gh_l[(ghw + 4 + b2) * 96 + 32 + dd];
      float nv1 = gh_l[(ghw + b2) * 96 + 64 + dd] + gh_l[(ghw + 4 + b2) * 96 + 64 + dd];
      float rg0 = sigm(pr0 + r0 + bh_r);
      float zg0 = sigm(pz0 + z0 + bh_z);
      float ng0 = tanh_f(pn0 + rg0 * (nv0 + bh_n));
      hf0 = (1.f - zg0) * ng0 + zg0 * hf0;
      unsigned short hi0 = f2b(hf0);
      hnxt[bp * 136 + d] = hi0;
      hnxt[(4 + bp) * 136 + d] = f2b(hf0 - b2f(hi0));
      ob0[ss] = hf0;
      float rg1 = sigm(pr1 + r1 + bh_r);
      float zg1 = sigm(pz1 + z1 + bh_z);
      float ng1 = tanh_f(pn1 + rg1 * (nv1 + bh_n));
      hf1 = (1.f - zg1) * ng1 + zg1 * hf1;
      unsigned short hi1 = f2b(hf1);
      hnxt[b2 * 136 + d] = hi1;
      hnxt[(4 + b2) * 136 + d] = f2b(hf1 - b2f(hi1));
      ob1[ss] = hf1;
      __syncthreads();
    }
    // flush 8 buffered steps (drained at next step's barrier, amortized)
    #pragma unroll
    for (int qq = 0; qq < 8; ++qq) {
      int sq = sb + qq;
      int tq = dir ? (T - 1 - sq) : sq;
      outf[(size_t)(bp * T + tq) * H2 + colOff + d] = ob0[qq];
      outf[(size_t)(b2 * T + tq) * H2 + colOff + d] = ob1[qq];
    }
  }
}

// ---------------- hi/lo decomposition (post-GRU, parallel) ----------------

__global__ void k_hilo1(const float* __restrict__ hl_f, const float* __restrict__ hr_f,
                        unsigned short* __restrict__ hl_hi, unsigned short* __restrict__ hl_lo,
                        unsigned short* __restrict__ hr_hi, unsigned short* __restrict__ hr_lo,
                        unsigned short* __restrict__ agg_hi, unsigned short* __restrict__ agg_lo) {
  int seg = blockIdx.y;
  int i = blockIdx.x * 256 + threadIdx.x;      // i < M*H2
  if (seg == 0) {
    float v = hl_f[i];
    unsigned short hi = f2b(v);
    hl_hi[i] = hi; hl_lo[i] = f2b(v - b2f(hi));
  } else if (seg == 1) {
    float v = hr_f[i];
    unsigned short hi = f2b(v);
    hr_hi[i] = hi; hr_lo[i] = f2b(v - b2f(hi));
  } else {
    float v = hr_f[i];
    unsigned short hi = f2b(v);
    size_t o = (size_t)(i >> 8) * H12 + (i & 255);
    agg_hi[o] = hi; agg_lo[o] = f2b(v - b2f(hi));
  }
}

__global__ void k_hilo2(const float* __restrict__ src,
                        unsigned short* __restrict__ dhi, unsigned short* __restrict__ dlo) {
  int i = blockIdx.x * 256 + threadIdx.x;
  float v = src[i];
  unsigned short hi = f2b(v);
  dhi[i] = hi; dlo[i] = f2b(v - b2f(hi));
}

// ---------------- cheap scores: co-attention (c), bilinear (b), subtractive (m) ----

__global__ __launch_bounds__(256) void k_score_cmb(
    const float* __restrict__ Hc, const float* __restrict__ Rc,
    const float* __restrict__ Hm, const float* __restrict__ Rm,
    const float* __restrict__ HB, const float* __restrict__ hrf,
    const float* __restrict__ vcf, const float* __restrict__ vmf,
    float* __restrict__ S) {
  int bi = blockIdx.x, b = bi >> 8;
  __shared__ __align__(16) float rc_l[128];
  __shared__ __align__(16) float rm_l[128];
  __shared__ __align__(16) float vc_l[128];
  __shared__ __align__(16) float vm_l[128];
  __shared__ __align__(16) float hr_l[256];
  int tid = threadIdx.x;
  if (tid < 128) {
    rc_l[tid] = Rc[(size_t)bi * 128 + tid];
    rm_l[tid] = Rm[(size_t)bi * 128 + tid];
    vc_l[tid] = vcf[tid];
    vm_l[tid] = vmf[tid];
  }
  hr_l[tid] = hrf[(size_t)bi * 256 + tid];
  __syncthreads();
  int j = tid;
  const float4* hc4 = (const float4*)(Hc + (size_t)(b * 256 + j) * 128);
  const float4* hm4 = (const float4*)(Hm + (size_t)(b * 256 + j) * 128);
  const float4* hb4 = (const float4*)(HB + (size_t)(b * 256 + j) * 256);
  const float4* rc4 = (const float4*)rc_l;
  const float4* rm4 = (const float4*)rm_l;
  const float4* vc4 = (const float4*)vc_l;
  const float4* vm4 = (const float4*)vm_l;
  const float4* hr4 = (const float4*)hr_l;
  float sc = 0.f, sm = 0.f, sb = 0.f;
  #pragma unroll 4
  for (int k = 0; k < 32; ++k) {
    float4 a = hc4[k], c = rc4[k], v = vc4[k];
    sc += v.x * tanh_f(a.x + c.x) + v.y * tanh_f(a.y + c.y)
        + v.z * tanh_f(a.z + c.z) + v.w * tanh_f(a.w + c.w);
    float4 am = hm4[k], cm = rm4[k], vv = vm4[k];
    sm += vv.x * tanh_f(am.x - cm.x) + vv.y * tanh_f(am.y - cm.y)
        + vv.z * tanh_f(am.z - cm.z) + vv.w * tanh_f(am.w - cm.w);
  }
  #pragma unroll 4
  for (int k = 0; k < 64; ++k) {
    float4 p = hb4[k], h = hr4[k];
    sb += p.x * h.x + p.y * h.y + p.z * h.z + p.w * h.w;
  }
  size_t o = (size_t)bi * 256 + j;
  S[(size_t)STY * 1 + o] = sc;   // c
  S[(size_t)STY * 3 + o] = sb;   // b
  S[(size_t)STY * 4 + o] = sm;   // m
}

// ---------------- expensive scores: S[i,j] = v . tanh(W (X_j o R_i)) ------------

struct SdArgs {
  const unsigned short* Xhi[2]; const unsigned short* Xlo[2];
  const float* Rf; const float* Wt[2]; const float* vt[2]; float* So[2];
};

__global__ __launch_bounds__(256) void k_score_ds(SdArgs a) {
  int which = blockIdx.y;
  const unsigned short* Xhi = a.Xhi[which];
  const unsigned short* Xlo = a.Xlo[which];
  const float* W = a.Wt[which];
  const float* v = a.vt[which];
  float* Sout = a.So[which];
  int bi = blockIdx.x, b = bi >> 8;
  __shared__ __align__(16) unsigned short w_lds[64 * 264];
  __shared__ float hr_l[256];
  __shared__ float sp[4][256];
  int tid = threadIdx.x, lane = tid & 63, w = tid >> 6, quad = lane >> 4, l16 = lane & 15;
  hr_l[tid] = a.Rf[(size_t)bi * 256 + tid];
  #pragma unroll
  for (int ww = 0; ww < 4; ++ww) sp[ww][tid] = 0.f;
  __syncthreads();
  for (int p = 0; p < 2; ++p) {
    for (int idx = tid; idx < 64 * 256; idx += 256) {
      int kl = idx >> 8, dc = idx & 255;
      w_lds[kl * 264 + dc] = f2b(W[(size_t)(p * 64 + kl) * 256 + dc] * hr_l[dc]);
    }
    __syncthreads();
    int kcol = w * 16 + l16;
    float vv = v[p * 64 + kcol];
    s16x8 bfr[8];
    #pragma unroll
    for (int kc = 0; kc < 8; ++kc)
      bfr[kc] = ldfrag(w_lds + kcol * 264 + kc * 32 + quad * 8);
    for (int jt = 0; jt < 16; ++jt) {
      size_t rowoff = (size_t)(b * 256 + jt * 16 + l16) * 256 + quad * 8;
      f32x4 acc = f32x4{0.f, 0.f, 0.f, 0.f};
      #pragma unroll
      for (int kc = 0; kc < 8; ++kc) {
        acc = mfma16(ldfrag(Xhi + rowoff + kc * 32), bfr[kc], acc);
        acc = mfma16(ldfrag(Xlo + rowoff + kc * 32), bfr[kc], acc);
      }
      #pragma unroll
      for (int r = 0; r < 4; ++r) {
        float t = tanh_f(acc[r]) * vv;
        t += __shfl_xor(t, 1); t += __shfl_xor(t, 2);
        t += __shfl_xor(t, 4); t += __shfl_xor(t, 8);
        if (l16 == 0) sp[w][jt * 16 + quad * 4 + r] += t;
      }
    }
    __syncthreads();
  }
  Sout[(size_t)bi * 256 + tid] = sp[0][tid] + sp[1][tid] + sp[2][tid] + sp[3][tid];
}

// ---------------- softmax over j for all 5 score types (fp32 out) --------------

__global__ __launch_bounds__(256) void k_softmax(const float* __restrict__ S,
                                                 float* __restrict__ P) {
  int bi = blockIdx.x, tid = threadIdx.x;
  __shared__ float red[4];
  for (int type = 0; type < 5; ++type) {
    size_t o = (size_t)type * STY + (size_t)bi * 256 + tid;
    float x = S[o];
    float m = x;
    for (int dl = 32; dl; dl >>= 1) m = fmaxf(m, __shfl_xor(m, dl));
    if ((tid & 63) == 0) red[tid >> 6] = m;
    __syncthreads();
    m = fmaxf(fmaxf(red[0], red[1]), fmaxf(red[2], red[3]));
    __syncthreads();
    float e = __expf(x - m);
    float sum = e;
    for (int dl = 32; dl; dl >>= 1) sum += __shfl_xor(sum, dl);
    if ((tid & 63) == 0) red[tid >> 6] = sum;
    __syncthreads();
    sum = red[0] + red[1] + red[2] + red[3];
    P[o] = e / sum;
    __syncthreads();
  }
}

// ---------------- 5 weighted sums into agg (hi/lo bf16 out) ----------------

__global__ __launch_bounds__(256) void k_wsum(const float* __restrict__ P,
    const float* __restrict__ hl_f, const float* __restrict__ hr_f,
    unsigned short* __restrict__ ahi, unsigned short* __restrict__ alo) {
  int it = blockIdx.x, type = blockIdx.y, b = blockIdx.z;
  __shared__ float p_l[8][256];
  int tid = threadIdx.x;
  for (int ii = 0; ii < 8; ++ii)
    p_l[ii][tid] = P[((size_t)(type * 4 + b) * 256 + it * 8 + ii) * 256 + tid];
  __syncthreads();
  const float* src = (type == 0 ? hr_f : hl_f) + (size_t)b * 256 * 256;
  float acc[8] = {0.f, 0.f, 0.f, 0.f, 0.f, 0.f, 0.f, 0.f};
  for (int j = 0; j < 256; ++j) {
    float hv = src[(size_t)j * 256 + tid];
    #pragma unroll
    for (int ii = 0; ii < 8; ++ii) acc[ii] += p_l[ii][j] * hv;
  }
  int off = 256 * (1 + type);      // agg: [hr | pts | ptc | ptd | ptb | ptm]
  #pragma unroll
  for (int ii = 0; ii < 8; ++ii) {
    float vv = acc[ii];
    unsigned short hi = f2b(vv);
    size_t o = (size_t)(b * 256 + it * 8 + ii) * H12 + off + tid;
    ahi[o] = hi;
    alo[o] = f2b(vv - b2f(hi));
  }
}

// ---------------- fused tail: pooling over hl + final attention + predict -------

__global__ __launch_bounds__(256) void k_tail(const float* __restrict__ Hp,
    const float* __restrict__ hl_f, const float* __restrict__ vpf,
    const float* __restrict__ Wc2f, const float* __restrict__ Arc,
    const float* __restrict__ ar_f, const float* __restrict__ vcf,
    const float* __restrict__ Wpredf, float* __restrict__ out) {
  int b = blockIdx.x, tid = threadIdx.x;
  __shared__ float vl[128], wl[256], rvec[256], rlcl[128], red[4];
  if (tid < 128) vl[tid] = vpf[tid];
  __syncthreads();
  // pool scores over hl
  const float* hp = Hp + (size_t)(b * 256 + tid) * 128;
  float s = 0.f;
  for (int k = 0; k < 128; ++k) s += vl[k] * tanh_f(hp[k]);
  float m = s;
  for (int dl = 32; dl; dl >>= 1) m = fmaxf(m, __shfl_xor(m, dl));
  if ((tid & 63) == 0) red[tid >> 6] = m;
  __syncthreads();
  m = fmaxf(fmaxf(red[0], red[1]), fmaxf(red[2], red[3]));
  __syncthreads();
  float e = __expf(s - m);
  float sum = e;
  for (int dl = 32; dl; dl >>= 1) sum += __shfl_xor(sum, dl);
  if ((tid & 63) == 0) red[tid >> 6] = sum;
  __syncthreads();
  sum = red[0] + red[1] + red[2] + red[3];
  wl[tid] = e / sum;
  __syncthreads();
  float acc = 0.f;
  for (int t = 0; t < 256; ++t) acc += wl[t] * hl_f[(size_t)(b * 256 + t) * 256 + tid];
  rvec[tid] = acc;
  __syncthreads();
  if (tid < 128) {
    float a2 = 0.f;
    const float* wr = Wc2f + (size_t)tid * 256;
    for (int dk = 0; dk < 256; ++dk) a2 += rvec[dk] * wr[dk];
    rlcl[tid] = a2;
    vl[tid] = vcf[tid];
  }
  __syncthreads();
  // final attention over ar
  const float* ap = Arc + (size_t)(b * 256 + tid) * 128;
  float s2 = 0.f;
  for (int k = 0; k < 128; ++k) s2 += vl[k] * (ap[k] + rlcl[k]);
  m = s2;
  for (int dl = 32; dl; dl >>= 1) m = fmaxf(m, __shfl_xor(m, dl));
  if ((tid & 63) == 0) red[tid >> 6] = m;
  __syncthreads();
  m = fmaxf(fmaxf(red[0], red[1]), fmaxf(red[2], red[3]));
  __syncthreads();
  float e2 = __expf(s2 - m);
  float sum2 = e2;
  for (int dl = 32; dl; dl >>= 1) sum2 += __shfl_xor(sum2, dl);
  if ((tid & 63) == 0) red[tid >> 6] = sum2;
  __syncthreads();
  sum2 = red[0] + red[1] + red[2] + red[3];
  wl[tid] = e2 / sum2;
  __syncthreads();
  float acc2 = 0.f;
  for (int t = 0; t < 256; ++t) acc2 += wl[t] * ar_f[(size_t)(b * 256 + t) * 256 + tid];
  rvec[tid] = acc2;
  __syncthreads();
  if (tid < 2) {
    float o = 0.f;
    const float* wp = Wpredf + (size_t)tid * 256;
    for (int dk = 0; dk < 256; ++dk) o += rvec[dk] * wp[dk];
    out[b * 2 + tid] = sigm(o);
  }
}

// ---------------- host ----------------

extern "C" void kernel_launch(void* const* d_in, const int* in_sizes, int n_in,
                              void* d_out, int out_size, void* d_ws, size_t ws_size,
                              hipStream_t stream) {
  (void)in_sizes; (void)n_in; (void)out_size; (void)ws_size;
  const int* inputs = (const int*)d_in[0];
  const float* embed = (const float*)d_in[1];
  const float* lWih = (const float*)d_in[2];
  const float* lWhh = (const float*)d_in[3];
  const float* lbih = (const float*)d_in[4];
  const float* lbhh = (const float*)d_in[5];
  const float* rWih = (const float*)d_in[6];
  const float* rWhh = (const float*)d_in[7];
  const float* rbih = (const float*)d_in[8];
  const float* rbhh = (const float*)d_in[9];
  const float* aWih = (const float*)d_in[10];
  const float* aWhh = (const float*)d_in[11];
  const float* abih = (const float*)d_in[12];
  const float* abhh = (const float*)d_in[13];
  const float* Wc1 = (const float*)d_in[14];
  const float* Wc2 = (const float*)d_in[15];
  const float* vc  = (const float*)d_in[16];
  const float* Wb  = (const float*)d_in[17];
  const float* Wd  = (const float*)d_in[18];
  const float* vd  = (const float*)d_in[19];
  const float* Wm  = (const float*)d_in[20];
  const float* vmv = (const float*)d_in[21];
  const float* Wsw = (const float*)d_in[22];
  const float* vsv = (const float*)d_in[23];
  const float* Wp  = (const float*)d_in[24];
  const float* vp  = (const float*)d_in[25];
  const float* Wpred = (const float*)d_in[26];

  char* ws = (char*)d_ws;
  size_t off = 0;
  auto alloc = [&](size_t bytes) -> void* {
    void* p = ws + off;
    off += (bytes + 255) & ~(size_t)255;
    return p;
  };
  unsigned short* xhi = (unsigned short*)alloc((size_t)M * EP * 2);
  unsigned short* xlo = (unsigned short*)alloc((size_t)M * EP * 2);
  unsigned short* wpad = (unsigned short*)alloc((size_t)4 * H3 * EP * 2);
  unsigned short* Whh_b = (unsigned short*)alloc((size_t)6 * H3 * H * 2);
  unsigned short* aWih_b = (unsigned short*)alloc((size_t)2 * H3 * H12 * 2);
  unsigned short* Wc1_b = (unsigned short*)alloc((size_t)H * H2 * 2);
  unsigned short* Wc2_b = (unsigned short*)alloc((size_t)H * H2 * 2);
  unsigned short* Wm_b  = (unsigned short*)alloc((size_t)H * H2 * 2);
  unsigned short* Wp_b  = (unsigned short*)alloc((size_t)H * H2 * 2);
  unsigned short* Wb_b  = (unsigned short*)alloc((size_t)H2 * H2 * 2);
  // region1 hosts pre_lr -> S -> pre_a (strictly sequential lifetimes)
  char* region1 = (char*)alloc((size_t)4 * M * H3 * 4);
  float* pre_lr = (float*)region1;
  float* S      = (float*)region1;
  float* pre_a  = (float*)region1;
  float* hl_f = (float*)alloc((size_t)M * H2 * 4);
  float* hr_f = (float*)alloc((size_t)M * H2 * 4);
  unsigned short* hl_hi = (unsigned short*)alloc((size_t)M * H2 * 2);
  unsigned short* hl_lo = (unsigned short*)alloc((size_t)M * H2 * 2);
  unsigned short* hr_hi = (unsigned short*)alloc((size_t)M * H2 * 2);
  unsigned short* hr_lo = (unsigned short*)alloc((size_t)M * H2 * 2);
  float* Hc = (float*)alloc((size_t)M * H * 4);
  float* Rc = (float*)alloc((size_t)M * H * 4);
  float* Hm = (float*)alloc((size_t)M * H * 4);
  float* Rm = (float*)alloc((size_t)M * H * 4);
  float* Hp = (float*)alloc((size_t)M * H * 4);
  float* HB = (float*)alloc((size_t)M * H2 * 4);
  float* P = (float*)alloc((size_t)5 * STY * 4);
  unsigned short* agg_hi = (unsigned short*)alloc((size_t)M * H12 * 2);
  unsigned short* agg_lo = (unsigned short*)alloc((size_t)M * H12 * 2);
  float* ar_f = (float*)alloc((size_t)M * H2 * 4);
  unsigned short* ar_hi = (unsigned short*)alloc((size_t)M * H2 * 2);
  unsigned short* ar_lo = (unsigned short*)alloc((size_t)M * H2 * 2);
  float* Arc = (float*)alloc((size_t)M * H * 4);

  // 1. staging: 9x cvt + embed + padw
  StageArgs sa{};
  sa.cs[0] = lWhh;  sa.cd[0] = Whh_b;                 sa.cn[0] = 2 * H3 * H;
  sa.cs[1] = rWhh;  sa.cd[1] = Whh_b + 2 * H3 * H;    sa.cn[1] = 2 * H3 * H;
  sa.cs[2] = aWhh;  sa.cd[2] = Whh_b + 4 * H3 * H;    sa.cn[2] = 2 * H3 * H;
  sa.cs[3] = aWih;  sa.cd[3] = aWih_b;                sa.cn[3] = 2 * H3 * H12;
  sa.cs[4] = Wc1;   sa.cd[4] = Wc1_b;                 sa.cn[4] = H * H2;
  sa.cs[5] = Wc2;   sa.cd[5] = Wc2_b;                 sa.cn[5] = H * H2;
  sa.cs[6] = Wm;    sa.cd[6] = Wm_b;                  sa.cn[6] = H * H2;
  sa.cs[7] = Wp;    sa.cd[7] = Wp_b;                  sa.cn[7] = H * H2;
  sa.cs[8] = Wb;    sa.cd[8] = Wb_b;                  sa.cn[8] = H2 * H2;
  sa.idx = inputs; sa.emb = embed; sa.xhi = xhi; sa.xlo = xlo;
  sa.lW = lWih; sa.rW = rWih; sa.wpad = wpad;
  k_stage<<<dim3((2 * H3 * H12 + 255) / 256, 11), dim3(256), 0, stream>>>(sa);

  // 2. input projections for l/r GRUs
  GemmBatch ga{};
  const float* biases[4] = { lbih, lbih + H3, rbih, rbih + H3 };
  for (int u = 0; u < 4; ++u)
    ga.d[u] = GemmDesc{ xhi, xlo, wpad + (size_t)u * H3 * EP, biases[u],
                        pre_lr + (size_t)u * M * H3, H3, EP };
  k_gemm<<<dim3(16, 6, 4), dim3(256), 0, stream>>>(ga);

  // 3. l/r recurrences
  RecArgs r1{};
  r1.whh[0] = Whh_b;               r1.whh[1] = Whh_b + H3 * H;
  r1.whh[2] = Whh_b + 2 * H3 * H;  r1.whh[3] = Whh_b + 3 * H3 * H;
  for (int u = 0; u < 4; ++u) r1.pre[u] = pre_lr + (size_t)u * M * H3;
  r1.outf[0] = r1.outf[1] = hl_f; r1.outf[2] = r1.outf[3] = hr_f;
  r1.bhh[0] = lbhh; r1.bhh[1] = lbhh + H3; r1.bhh[2] = rbhh; r1.bhh[3] = rbhh + H3;
  r1.colOff[0] = 0; r1.colOff[1] = H; r1.colOff[2] = 0; r1.colOff[3] = H;
  r1.dir[0] = 0; r1.dir[1] = 1; r1.dir[2] = 0; r1.dir[3] = 1;
  k_gru<<<dim3(4), dim3(256), 0, stream>>>(r1);

  // 4. hi/lo staging of hl/hr + agg hr-copy
  k_hilo1<<<dim3(1024, 3), dim3(256), 0, stream>>>(hl_f, hr_f, hl_hi, hl_lo,
                                                   hr_hi, hr_lo, agg_hi, agg_lo);

  // 5. projection GEMMs for scores/pooling
  GemmBatch gbB{};
  gbB.d[0] = GemmDesc{ hl_hi, hl_lo, Wc1_b, nullptr, Hc, H, H2 };
  gbB.d[1] = GemmDesc{ hr_hi, hr_lo, Wc2_b, nullptr, Rc, H, H2 };
  gbB.d[2] = GemmDesc{ hl_hi, hl_lo, Wm_b, nullptr, Hm, H, H2 };
  gbB.d[3] = GemmDesc{ hr_hi, hr_lo, Wm_b, nullptr, Rm, H, H2 };
  gbB.d[4] = GemmDesc{ hl_hi, hl_lo, Wb_b, nullptr, HB, H2, H2 };
  gbB.d[5] = GemmDesc{ hl_hi, hl_lo, Wp_b, nullptr, Hp, H, H2 };
  k_gemm<<<dim3(16, 4, 6), dim3(256), 0, stream>>>(gbB);

  // 6-8. scores + softmax
  k_score_cmb<<<dim3(M), dim3(256), 0, stream>>>(Hc, Rc, Hm, Rm, HB, hr_f, vc, vmv, S);
  SdArgs sd{};
  sd.Xhi[0] = hl_hi; sd.Xlo[0] = hl_lo; sd.Wt[0] = Wd;  sd.vt[0] = vd;
  sd.So[0] = S + (size_t)2 * STY;
  sd.Xhi[1] = hr_hi; sd.Xlo[1] = hr_lo; sd.Wt[1] = Wsw; sd.vt[1] = vsv;
  sd.So[1] = S + (size_t)0 * STY;
  sd.Rf = hr_f;
  k_score_ds<<<dim3(M, 2), dim3(256), 0, stream>>>(sd);
  k_softmax<<<dim3(M), dim3(256), 0, stream>>>(S, P);

  // 9. weighted sums into agg
  k_wsum<<<dim3(32, 5, 4), dim3(256), 0, stream>>>(P, hl_f, hr_f, agg_hi, agg_lo);

  // 10. agg GRU input projection
  GemmBatch gc{};
  gc.d[0] = GemmDesc{ agg_hi, agg_lo, aWih_b, abih, pre_a, H3, H12 };
  gc.d[1] = GemmDesc{ agg_hi, agg_lo, aWih_b + (size_t)H3 * H12, abih + H3,
                      pre_a + (size_t)M * H3, H3, H12 };
  k_gemm<<<dim3(16, 6, 2), dim3(256), 0, stream>>>(gc);

  // 11. agg recurrence
  RecArgs r2{};
  r2.whh[0] = Whh_b + 4 * H3 * H; r2.whh[1] = Whh_b + 5 * H3 * H;
  r2.whh[2] = r2.whh[3] = Whh_b + 4 * H3 * H;
  r2.pre[0] = pre_a; r2.pre[1] = pre_a + (size_t)M * H3;
  r2.pre[2] = r2.pre[3] = pre_a;
  r2.outf[0] = r2.outf[1] = r2.outf[2] = r2.outf[3] = ar_f;
  r2.bhh[0] = abhh; r2.bhh[1] = abhh + H3; r2.bhh[2] = r2.bhh[3] = abhh;
  r2.colOff[0] = 0; r2.colOff[1] = H; r2.colOff[2] = r2.colOff[3] = 0;
  r2.dir[0] = 0; r2.dir[1] = 1; r2.dir[2] = r2.dir[3] = 0;
  k_gru<<<dim3(2), dim3(256), 0, stream>>>(r2);

  // 12-13. ar hi/lo + Arc GEMM
  k_hilo2<<<dim3(1024), dim3(256), 0, stream>>>(ar_f, ar_hi, ar_lo);
  GemmBatch gd{};
  gd.d[0] = GemmDesc{ ar_hi, ar_lo, Wc1_b, nullptr, Arc, H, H2 };
  k_gemm<<<dim3(16, 2, 1), dim3(256), 0, stream>>>(gd);

  // 14. fused pool + final attention + prediction
  k_tail<<<dim3(4), dim3(256), 0, stream>>>(Hp, hl_f, vp, Wc2, Arc, ar_f, vc, Wpred,
                                            (float*)d_out);
}

// Round 6
// 1038.003 us; speedup vs baseline: 1.3817x; 1.2170x over previous
//
#include <hip/hip_runtime.h>

// MANNet forward, MI355X gfx950. Inputs fp32 (+int32 ids), output fp32.
// MFMA paths: A compensated bf16 hi+lo (GEMMs/GRU), W single-rounded bf16.
// R6: k_score_ds rewritten — operand swap puts the v-dot reduction in-register
// (k = quad*4+r), no shuffles; X hi-only; 4 passes x 32 k-rows -> 26 KB LDS,
// 6 blocks/CU.

#define DEV static __device__ __forceinline__

typedef __attribute__((ext_vector_type(4))) float f32x4;
typedef __attribute__((ext_vector_type(8))) short s16x8;
typedef __attribute__((ext_vector_type(4))) unsigned int u32x4;

constexpr int T = 256, E = 300, EP = 320, H = 128, H2 = 256, H3 = 384, H12 = 1536;
constexpr int M = 1024;            // B*T
constexpr int STY = 262144;        // 4*T*T elements per score type

DEV float b2f(unsigned short h) { return __uint_as_float(((unsigned)h) << 16); }
DEV unsigned short f2b(float f) {
  unsigned u = __float_as_uint(f);
  u += 0x7fff + ((u >> 16) & 1);            // RNE
  return (unsigned short)(u >> 16);
}
DEV float sigm(float x) { return 1.f / (1.f + __expf(-x)); }
DEV float tanh_f(float x) { float e = __expf(2.f * x); return 1.f - 2.f / (e + 1.f); }

DEV s16x8 ldfrag(const unsigned short* p) {
  u32x4 v = *(const u32x4*)p;
  return __builtin_bit_cast(s16x8, v);
}
DEV f32x4 mfma16(s16x8 a, s16x8 b, f32x4 c) {
  return __builtin_amdgcn_mfma_f32_16x16x32_bf16(a, b, c, 0, 0, 0);
}

// ---------------- fused staging: 9x cvt + embed + padw ----------------

struct StageArgs {
  const float* cs[9]; unsigned short* cd[9]; int cn[9];
  const int* idx; const float* emb; unsigned short* xhi; unsigned short* xlo;
  const float* lW; const float* rW; unsigned short* wpad;
};

__global__ void k_stage(StageArgs sa) {
  int seg = blockIdx.y;
  int i = blockIdx.x * 256 + threadIdx.x;
  if (seg < 9) {
    if (i < sa.cn[seg]) sa.cd[seg][i] = f2b(sa.cs[seg][i]);
    return;
  }
  if (seg == 9) {                       // embedding gather -> padded hi/lo
    if (i >= M * EP) return;
    int m = i / EP, e = i - m * EP;
    int r = sa.idx[m];
    float v = (e < E) ? sa.emb[(size_t)r * E + e] : 0.f;
    unsigned short hi = f2b(v);
    sa.xhi[i] = hi;
    sa.xlo[i] = f2b(v - b2f(hi));
    return;
  }
  // seg 10: Wih (l,r) -> bf16, K padded 300->320
  if (i >= 4 * H3 * EP) return;
  int e = i % EP, n = (i / EP) % H3, uu = i / (EP * H3);
  const float* src = (uu < 2 ? sa.lW : sa.rW) + (size_t)((uu & 1) * H3 + n) * E;
  sa.wpad[i] = (e < E) ? f2b(src[e]) : (unsigned short)0;
}

// ---------------- generic GEMM: C = (Ahi+Alo) @ W^T (+bias), fp32 out ----------

struct GemmDesc {
  const unsigned short* Ahi; const unsigned short* Alo; const unsigned short* W;
  const float* bias; float* Cf; int N; int K;
};
struct GemmBatch { GemmDesc d[8]; };

__global__ __launch_bounds__(256) void k_gemm(GemmBatch gb) {
  GemmDesc g = gb.d[blockIdx.z];
  int nb = blockIdx.y * 64;
  if (nb >= g.N) return;
  int mb = blockIdx.x * 64;
  int lane = threadIdx.x & 63, w = threadIdx.x >> 6, quad = lane >> 4, l16 = lane & 15;
  int K = g.K;
  const unsigned short* Ahp = g.Ahi + (size_t)(mb + w * 16 + l16) * K + quad * 8;
  const unsigned short* Alp = g.Alo + (size_t)(mb + w * 16 + l16) * K + quad * 8;
  const unsigned short* Wp = g.W + (size_t)(nb + l16) * K + quad * 8;
  f32x4 acc[4];
  #pragma unroll
  for (int nt = 0; nt < 4; ++nt) acc[nt] = f32x4{0.f, 0.f, 0.f, 0.f};
  for (int k = 0; k < K; k += 32) {
    s16x8 ah = ldfrag(Ahp + k);
    s16x8 al = ldfrag(Alp + k);
    #pragma unroll
    for (int nt = 0; nt < 4; ++nt) {
      s16x8 b = ldfrag(Wp + (size_t)nt * 16 * K + k);
      acc[nt] = mfma16(ah, b, acc[nt]);
      acc[nt] = mfma16(al, b, acc[nt]);
    }
  }
  int mr0 = mb + w * 16 + quad * 4;
  #pragma unroll
  for (int nt = 0; nt < 4; ++nt) {
    int col = nb + nt * 16 + l16;
    float bv = g.bias ? g.bias[col] : 0.f;
    #pragma unroll
    for (int r = 0; r < 4; ++r)
      g.Cf[(size_t)(mr0 + r) * g.N + col] = acc[nt][r] + bv;
  }
}

// ---------------- GRU recurrence: 1 barrier/step ----------------

struct RecArgs {
  const unsigned short* whh[4];   // staged bf16 (384x128)
  const float* pre[4];
  float* outf[4];
  const float* bhh[4];            // fp32, 384
  int colOff[4];
  int dir[4];
};

__global__ __launch_bounds__(256) void k_gru(RecArgs ra) {
  int u = blockIdx.x;
  __shared__ __align__(16) unsigned short hs[2][16 * 136];
  __shared__ float gh_l[4 * 8 * 96];
  int tid = threadIdx.x, lane = tid & 63, w = tid >> 6;
  int quad = lane >> 4, l16 = lane & 15;
  for (int i = tid; i < 2 * 16 * 136; i += 256) ((unsigned short*)hs)[i] = 0;
  const unsigned short* whh = ra.whh[u];
  s16x8 bq[6][4];
  #pragma unroll
  for (int nt = 0; nt < 6; ++nt) {
    int row = (nt >> 1) * 128 + w * 32 + (nt & 1) * 16 + l16;
    #pragma unroll
    for (int kc = 0; kc < 4; ++kc)
      bq[nt][kc] = ldfrag(whh + (size_t)row * H + kc * 32 + quad * 8);
  }
  const float* bhh = ra.bhh[u];
  const float* pre = ra.pre[u];
  float* outf = ra.outf[u];
  int colOff = ra.colOff[u], dir = ra.dir[u];
  int dd = lane & 31, bp = lane >> 5, b2 = bp + 2;
  int d = w * 32 + dd;
  float bh_r = bhh[d], bh_z = bhh[d + 128], bh_n = bhh[d + 256];
  float hf0 = 0.f, hf1 = 0.f;
  float ob0[8], ob1[8];
  int ghw = w * 8;
  int t0 = dir ? (T - 1) : 0;
  {
    const float* q0 = pre + (size_t)(bp * T + t0) * H3 + d;
    const float* q1 = pre + (size_t)(b2 * T + t0) * H3 + d;
    ob0[0] = q0[0]; ob0[1] = q0[128]; ob0[2] = q0[256];
    ob1[0] = q1[0]; ob1[1] = q1[128]; ob1[2] = q1[256];
  }
  float n_pr0 = ob0[0], n_pz0 = ob0[1], n_pn0 = ob0[2];
  float n_pr1 = ob1[0], n_pz1 = ob1[1], n_pn1 = ob1[2];
  __syncthreads();
  for (int sb = 0; sb < T; sb += 8) {
    #pragma unroll
    for (int ss = 0; ss < 8; ++ss) {
      int s = sb + ss;
      float pr0 = n_pr0, pz0 = n_pz0, pn0 = n_pn0;
      float pr1 = n_pr1, pz1 = n_pz1, pn1 = n_pn1;
      int sn = (s + 1 < T) ? (s + 1) : s;
      int tn = dir ? (T - 1 - sn) : sn;
      const float* f0 = pre + (size_t)(bp * T + tn) * H3 + d;
      const float* f1 = pre + (size_t)(b2 * T + tn) * H3 + d;
      n_pr0 = f0[0]; n_pz0 = f0[128]; n_pn0 = f0[256];
      n_pr1 = f1[0]; n_pz1 = f1[128]; n_pn1 = f1[256];
      const unsigned short* hcur = hs[ss & 1];
      unsigned short* hnxt = hs[(ss & 1) ^ 1];
      s16x8 ah[4];
      #pragma unroll
      for (int kc = 0; kc < 4; ++kc)
        ah[kc] = ldfrag(hcur + l16 * 136 + kc * 32 + quad * 8);
      f32x4 acc[6];
      #pragma unroll
      for (int nt = 0; nt < 6; ++nt) acc[nt] = f32x4{0.f, 0.f, 0.f, 0.f};
      #pragma unroll
      for (int kc = 0; kc < 4; ++kc) {
        #pragma unroll
        for (int nt = 0; nt < 6; ++nt)
          acc[nt] = mfma16(ah[kc], bq[nt][kc], acc[nt]);
      }
      if (quad < 2) {
        #pragma unroll
        for (int nt = 0; nt < 6; ++nt) {
          int gcol = (nt >> 1) * 32 + (nt & 1) * 16 + l16;
          #pragma unroll
          for (int r = 0; r < 4; ++r)
            gh_l[(ghw + quad * 4 + r) * 96 + gcol] = acc[nt][r];
        }
      }
      __asm__ volatile("s_waitcnt lgkmcnt(0)" ::: "memory");
      float r0 = gh_l[(ghw + bp) * 96 + dd]      + gh_l[(ghw + 4 + bp) * 96 + dd];
      float z0 = gh_l[(ghw + bp) * 96 + 32 + dd] + gh_l[(ghw + 4 + bp) * 96 + 32 + dd];
      float nv0 = gh_l[(ghw + bp) * 96 + 64 + dd] + gh_l[(ghw + 4 + bp) * 96 + 64 + dd];
      float r1 = gh_l[(ghw + b2) * 96 + dd]      + gh_l[(ghw + 4 + b2) * 96 + dd];
      float z1 = gh_l[(ghw + b2) * 96 + 32 + dd] + gh_l[(ghw + 4 + b2) * 96 + 32 + dd];
      float nv1 = gh_l[(ghw + b2) * 96 + 64 + dd] + gh_l[(ghw + 4 + b2) * 96 + 64 + dd];
      float rg0 = sigm(pr0 + r0 + bh_r);
      float zg0 = sigm(pz0 + z0 + bh_z);
      float ng0 = tanh_f(pn0 + rg0 * (nv0 + bh_n));
      hf0 = (1.f - zg0) * ng0 + zg0 * hf0;
      unsigned short hi0 = f2b(hf0);
      hnxt[bp * 136 + d] = hi0;
      hnxt[(4 + bp) * 136 + d] = f2b(hf0 - b2f(hi0));
      ob0[ss] = hf0;
      float rg1 = sigm(pr1 + r1 + bh_r);
      float zg1 = sigm(pz1 + z1 + bh_z);
      float ng1 = tanh_f(pn1 + rg1 * (nv1 + bh_n));
      hf1 = (1.f - zg1) * ng1 + zg1 * hf1;
      unsigned short hi1 = f2b(hf1);
      hnxt[b2 * 136 + d] = hi1;
      hnxt[(4 + b2) * 136 + d] = f2b(hf1 - b2f(hi1));
      ob1[ss] = hf1;
      __syncthreads();
    }
    #pragma unroll
    for (int qq = 0; qq < 8; ++qq) {
      int sq = sb + qq;
      int tq = dir ? (T - 1 - sq) : sq;
      outf[(size_t)(bp * T + tq) * H2 + colOff + d] = ob0[qq];
      outf[(size_t)(b2 * T + tq) * H2 + colOff + d] = ob1[qq];
    }
  }
}

// ---------------- hi/lo decomposition (post-GRU, parallel) ----------------

__global__ void k_hilo1(const float* __restrict__ hl_f, const float* __restrict__ hr_f,
                        unsigned short* __restrict__ hl_hi, unsigned short* __restrict__ hl_lo,
                        unsigned short* __restrict__ hr_hi, unsigned short* __restrict__ hr_lo,
                        unsigned short* __restrict__ agg_hi, unsigned short* __restrict__ agg_lo) {
  int seg = blockIdx.y;
  int i = blockIdx.x * 256 + threadIdx.x;      // i < M*H2
  if (seg == 0) {
    float v = hl_f[i];
    unsigned short hi = f2b(v);
    hl_hi[i] = hi; hl_lo[i] = f2b(v - b2f(hi));
  } else if (seg == 1) {
    float v = hr_f[i];
    unsigned short hi = f2b(v);
    hr_hi[i] = hi; hr_lo[i] = f2b(v - b2f(hi));
  } else {
    float v = hr_f[i];
    unsigned short hi = f2b(v);
    size_t o = (size_t)(i >> 8) * H12 + (i & 255);
    agg_hi[o] = hi; agg_lo[o] = f2b(v - b2f(hi));
  }
}

__global__ void k_hilo2(const float* __restrict__ src,
                        unsigned short* __restrict__ dhi, unsigned short* __restrict__ dlo) {
  int i = blockIdx.x * 256 + threadIdx.x;
  float v = src[i];
  unsigned short hi = f2b(v);
  dhi[i] = hi; dlo[i] = f2b(v - b2f(hi));
}

// ---------------- cheap scores: co-attention (c), bilinear (b), subtractive (m) ----

__global__ __launch_bounds__(256) void k_score_cmb(
    const float* __restrict__ Hc, const float* __restrict__ Rc,
    const float* __restrict__ Hm, const float* __restrict__ Rm,
    const float* __restrict__ HB, const float* __restrict__ hrf,
    const float* __restrict__ vcf, const float* __restrict__ vmf,
    float* __restrict__ S) {
  int bi = blockIdx.x, b = bi >> 8;
  __shared__ __align__(16) float rc_l[128];
  __shared__ __align__(16) float rm_l[128];
  __shared__ __align__(16) float vc_l[128];
  __shared__ __align__(16) float vm_l[128];
  __shared__ __align__(16) float hr_l[256];
  int tid = threadIdx.x;
  if (tid < 128) {
    rc_l[tid] = Rc[(size_t)bi * 128 + tid];
    rm_l[tid] = Rm[(size_t)bi * 128 + tid];
    vc_l[tid] = vcf[tid];
    vm_l[tid] = vmf[tid];
  }
  hr_l[tid] = hrf[(size_t)bi * 256 + tid];
  __syncthreads();
  int j = tid;
  const float4* hc4 = (const float4*)(Hc + (size_t)(b * 256 + j) * 128);
  const float4* hm4 = (const float4*)(Hm + (size_t)(b * 256 + j) * 128);
  const float4* hb4 = (const float4*)(HB + (size_t)(b * 256 + j) * 256);
  const float4* rc4 = (const float4*)rc_l;
  const float4* rm4 = (const float4*)rm_l;
  const float4* vc4 = (const float4*)vc_l;
  const float4* vm4 = (const float4*)vm_l;
  const float4* hr4 = (const float4*)hr_l;
  float sc = 0.f, sm = 0.f, sb = 0.f;
  #pragma unroll 4
  for (int k = 0; k < 32; ++k) {
    float4 a = hc4[k], c = rc4[k], v = vc4[k];
    sc += v.x * tanh_f(a.x + c.x) + v.y * tanh_f(a.y + c.y)
        + v.z * tanh_f(a.z + c.z) + v.w * tanh_f(a.w + c.w);
    float4 am = hm4[k], cm = rm4[k], vv = vm4[k];
    sm += vv.x * tanh_f(am.x - cm.x) + vv.y * tanh_f(am.y - cm.y)
        + vv.z * tanh_f(am.z - cm.z) + vv.w * tanh_f(am.w - cm.w);
  }
  #pragma unroll 4
  for (int k = 0; k < 64; ++k) {
    float4 p = hb4[k], h = hr4[k];
    sb += p.x * h.x + p.y * h.y + p.z * h.z + p.w * h.w;
  }
  size_t o = (size_t)bi * 256 + j;
  S[(size_t)STY * 1 + o] = sc;   // c
  S[(size_t)STY * 3 + o] = sb;   // b
  S[(size_t)STY * 4 + o] = sm;   // m
}

// ---------------- expensive scores: S[i,j] = v . tanh(W (X_j o R_i)) ------------
// Per (b,i): A = (W o R_i) rows k, B = X rows j. D: k = quad*4+r, j = l16 ->
// v-dot over k is an in-register sum (no shuffles). 4 passes x 32 k-rows.
// Wave (kh=w>>1, jh=w&1): krow = kh*16+l16, jt in [jh*8, jh*8+8).

struct SdArgs {
  const unsigned short* Xhi[2];
  const float* Rf; const float* Wt[2]; const float* vt[2]; float* So[2];
};

__global__ __launch_bounds__(256) void k_score_ds(SdArgs a) {
  int which = blockIdx.y;
  const unsigned short* Xhi = a.Xhi[which];
  const float* W = a.Wt[which];
  const float* v = a.vt[which];
  float* Sout = a.So[which];
  int bi = blockIdx.x, b = bi >> 8;
  __shared__ __align__(16) unsigned short w_lds[32 * 264];
  __shared__ __align__(16) float hr_l[256];
  __shared__ float sp[8][260];
  int tid = threadIdx.x, lane = tid & 63, w = tid >> 6, quad = lane >> 4, l16 = lane & 15;
  int kh = w >> 1, jh = w & 1;
  hr_l[tid] = a.Rf[(size_t)bi * 256 + tid];
  __syncthreads();
  for (int p = 0; p < 4; ++p) {
    // stage w = (W o R_i) rows [p*32, p*32+32) as bf16 (float4-vectorized)
    #pragma unroll
    for (int it = 0; it < 8; ++it) {
      int idx4 = it * 256 + tid;          // 0..2047
      int kl = idx4 >> 6, d4 = idx4 & 63;
      float4 w4 = ((const float4*)(W + (size_t)(p * 32 + kl) * 256))[d4];
      float4 h4 = ((const float4*)hr_l)[d4];
      unsigned long long pk =
          (unsigned long long)f2b(w4.x * h4.x)
        | ((unsigned long long)f2b(w4.y * h4.y) << 16)
        | ((unsigned long long)f2b(w4.z * h4.z) << 32)
        | ((unsigned long long)f2b(w4.w * h4.w) << 48);
      *(unsigned long long*)(w_lds + kl * 264 + d4 * 4) = pk;
    }
    __syncthreads();
    int krow = kh * 16 + l16;
    s16x8 afr[8];
    #pragma unroll
    for (int kc = 0; kc < 8; ++kc)
      afr[kc] = ldfrag(w_lds + krow * 264 + kc * 32 + quad * 8);
    float vv[4];
    #pragma unroll
    for (int r = 0; r < 4; ++r) vv[r] = v[p * 32 + kh * 16 + quad * 4 + r];
    #pragma unroll
    for (int jj = 0; jj < 8; ++jj) {
      int jt = jh * 8 + jj;
      const unsigned short* Xp = Xhi + (size_t)(b * 256 + jt * 16 + l16) * 256 + quad * 8;
      f32x4 acc = f32x4{0.f, 0.f, 0.f, 0.f};
      #pragma unroll
      for (int kc = 0; kc < 8; ++kc)
        acc = mfma16(afr[kc], ldfrag(Xp + kc * 32), acc);
      float s = tanh_f(acc[0]) * vv[0] + tanh_f(acc[1]) * vv[1]
              + tanh_f(acc[2]) * vv[2] + tanh_f(acc[3]) * vv[3];
      int j = jt * 16 + l16;
      if (p == 0) sp[kh * 4 + quad][j >= 256 ? 0 : j] = s;
      else        sp[kh * 4 + quad][j >= 256 ? 0 : j] += s;
    }
    __syncthreads();
  }
  float r = 0.f;
  #pragma unroll
  for (int q = 0; q < 8; ++q) r += sp[q][tid];
  Sout[(size_t)bi * 256 + tid] = r;
}

// ---------------- softmax over j for all 5 score types (fp32 out) --------------

__global__ __launch_bounds__(256) void k_softmax(const float* __restrict__ S,
                                                 float* __restrict__ P) {
  int bi = blockIdx.x, tid = threadIdx.x;
  __shared__ float red[4];
  for (int type = 0; type < 5; ++type) {
    size_t o = (size_t)type * STY + (size_t)bi * 256 + tid;
    float x = S[o];
    float m = x;
    for (int dl = 32; dl; dl >>= 1) m = fmaxf(m, __shfl_xor(m, dl));
    if ((tid & 63) == 0) red[tid >> 6] = m;
    __syncthreads();
    m = fmaxf(fmaxf(red[0], red[1]), fmaxf(red[2], red[3]));
    __syncthreads();
    float e = __expf(x - m);
    float sum = e;
    for (int dl = 32; dl; dl >>= 1) sum += __shfl_xor(sum, dl);
    if ((tid & 63) == 0) red[tid >> 6] = sum;
    __syncthreads();
    sum = red[0] + red[1] + red[2] + red[3];
    P[o] = e / sum;
    __syncthreads();
  }
}

// ---------------- 5 weighted sums into agg (hi/lo bf16 out) ----------------

__global__ __launch_bounds__(256) void k_wsum(const float* __restrict__ P,
    const float* __restrict__ hl_f, const float* __restrict__ hr_f,
    unsigned short* __restrict__ ahi, unsigned short* __restrict__ alo) {
  int it = blockIdx.x, type = blockIdx.y, b = blockIdx.z;
  __shared__ float p_l[8][256];
  int tid = threadIdx.x;
  for (int ii = 0; ii < 8; ++ii)
    p_l[ii][tid] = P[((size_t)(type * 4 + b) * 256 + it * 8 + ii) * 256 + tid];
  __syncthreads();
  const float* src = (type == 0 ? hr_f : hl_f) + (size_t)b * 256 * 256;
  float acc[8] = {0.f, 0.f, 0.f, 0.f, 0.f, 0.f, 0.f, 0.f};
  for (int j = 0; j < 256; ++j) {
    float hv = src[(size_t)j * 256 + tid];
    #pragma unroll
    for (int ii = 0; ii < 8; ++ii) acc[ii] += p_l[ii][j] * hv;
  }
  int off = 256 * (1 + type);      // agg: [hr | pts | ptc | ptd | ptb | ptm]
  #pragma unroll
  for (int ii = 0; ii < 8; ++ii) {
    float vv = acc[ii];
    unsigned short hi = f2b(vv);
    size_t o = (size_t)(b * 256 + it * 8 + ii) * H12 + off + tid;
    ahi[o] = hi;
    alo[o] = f2b(vv - b2f(hi));
  }
}

// ---------------- fused tail: pooling over hl + final attention + predict -------

__global__ __launch_bounds__(256) void k_tail(const float* __restrict__ Hp,
    const float* __restrict__ hl_f, const float* __restrict__ vpf,
    const float* __restrict__ Wc2f, const float* __restrict__ Arc,
    const float* __restrict__ ar_f, const float* __restrict__ vcf,
    const float* __restrict__ Wpredf, float* __restrict__ out) {
  int b = blockIdx.x, tid = threadIdx.x;
  __shared__ float vl[128], wl[256], rvec[256], rlcl[128], red[4];
  if (tid < 128) vl[tid] = vpf[tid];
  __syncthreads();
  const float* hp = Hp + (size_t)(b * 256 + tid) * 128;
  float s = 0.f;
  for (int k = 0; k < 128; ++k) s += vl[k] * tanh_f(hp[k]);
  float m = s;
  for (int dl = 32; dl; dl >>= 1) m = fmaxf(m, __shfl_xor(m, dl));
  if ((tid & 63) == 0) red[tid >> 6] = m;
  __syncthreads();
  m = fmaxf(fmaxf(red[0], red[1]), fmaxf(red[2], red[3]));
  __syncthreads();
  float e = __expf(s - m);
  float sum = e;
  for (int dl = 32; dl; dl >>= 1) sum += __shfl_xor(sum, dl);
  if ((tid & 63) == 0) red[tid >> 6] = sum;
  __syncthreads();
  sum = red[0] + red[1] + red[2] + red[3];
  wl[tid] = e / sum;
  __syncthreads();
  float acc = 0.f;
  for (int t = 0; t < 256; ++t) acc += wl[t] * hl_f[(size_t)(b * 256 + t) * 256 + tid];
  rvec[tid] = acc;
  __syncthreads();
  if (tid < 128) {
    float a2 = 0.f;
    const float* wr = Wc2f + (size_t)tid * 256;
    for (int dk = 0; dk < 256; ++dk) a2 += rvec[dk] * wr[dk];
    rlcl[tid] = a2;
    vl[tid] = vcf[tid];
  }
  __syncthreads();
  const float* ap = Arc + (size_t)(b * 256 + tid) * 128;
  float s2 = 0.f;
  for (int k = 0; k < 128; ++k) s2 += vl[k] * (ap[k] + rlcl[k]);
  m = s2;
  for (int dl = 32; dl; dl >>= 1) m = fmaxf(m, __shfl_xor(m, dl));
  if ((tid & 63) == 0) red[tid >> 6] = m;
  __syncthreads();
  m = fmaxf(fmaxf(red[0], red[1]), fmaxf(red[2], red[3]));
  __syncthreads();
  float e2 = __expf(s2 - m);
  float sum2 = e2;
  for (int dl = 32; dl; dl >>= 1) sum2 += __shfl_xor(sum2, dl);
  if ((tid & 63) == 0) red[tid >> 6] = sum2;
  __syncthreads();
  sum2 = red[0] + red[1] + red[2] + red[3];
  wl[tid] = e2 / sum2;
  __syncthreads();
  float acc2 = 0.f;
  for (int t = 0; t < 256; ++t) acc2 += wl[t] * ar_f[(size_t)(b * 256 + t) * 256 + tid];
  rvec[tid] = acc2;
  __syncthreads();
  if (tid < 2) {
    float o = 0.f;
    const float* wp = Wpredf + (size_t)tid * 256;
    for (int dk = 0; dk < 256; ++dk) o += rvec[dk] * wp[dk];
    out[b * 2 + tid] = sigm(o);
  }
}

// ---------------- host ----------------

extern "C" void kernel_launch(void* const* d_in, const int* in_sizes, int n_in,
                              void* d_out, int out_size, void* d_ws, size_t ws_size,
                              hipStream_t stream) {
  (void)in_sizes; (void)n_in; (void)out_size; (void)ws_size;
  const int* inputs = (const int*)d_in[0];
  const float* embed = (const float*)d_in[1];
  const float* lWih = (const float*)d_in[2];
  const float* lWhh = (const float*)d_in[3];
  const float* lbih = (const float*)d_in[4];
  const float* lbhh = (const float*)d_in[5];
  const float* rWih = (const float*)d_in[6];
  const float* rWhh = (const float*)d_in[7];
  const float* rbih = (const float*)d_in[8];
  const float* rbhh = (const float*)d_in[9];
  const float* aWih = (const float*)d_in[10];
  const float* aWhh = (const float*)d_in[11];
  const float* abih = (const float*)d_in[12];
  const float* abhh = (const float*)d_in[13];
  const float* Wc1 = (const float*)d_in[14];
  const float* Wc2 = (const float*)d_in[15];
  const float* vc  = (const float*)d_in[16];
  const float* Wb  = (const float*)d_in[17];
  const float* Wd  = (const float*)d_in[18];
  const float* vd  = (const float*)d_in[19];
  const float* Wm  = (const float*)d_in[20];
  const float* vmv = (const float*)d_in[21];
  const float* Wsw = (const float*)d_in[22];
  const float* vsv = (const float*)d_in[23];
  const float* Wp  = (const float*)d_in[24];
  const float* vp  = (const float*)d_in[25];
  const float* Wpred = (const float*)d_in[26];

  char* ws = (char*)d_ws;
  size_t off = 0;
  auto alloc = [&](size_t bytes) -> void* {
    void* p = ws + off;
    off += (bytes + 255) & ~(size_t)255;
    return p;
  };
  unsigned short* xhi = (unsigned short*)alloc((size_t)M * EP * 2);
  unsigned short* xlo = (unsigned short*)alloc((size_t)M * EP * 2);
  unsigned short* wpad = (unsigned short*)alloc((size_t)4 * H3 * EP * 2);
  unsigned short* Whh_b = (unsigned short*)alloc((size_t)6 * H3 * H * 2);
  unsigned short* aWih_b = (unsigned short*)alloc((size_t)2 * H3 * H12 * 2);
  unsigned short* Wc1_b = (unsigned short*)alloc((size_t)H * H2 * 2);
  unsigned short* Wc2_b = (unsigned short*)alloc((size_t)H * H2 * 2);
  unsigned short* Wm_b  = (unsigned short*)alloc((size_t)H * H2 * 2);
  unsigned short* Wp_b  = (unsigned short*)alloc((size_t)H * H2 * 2);
  unsigned short* Wb_b  = (unsigned short*)alloc((size_t)H2 * H2 * 2);
  char* region1 = (char*)alloc((size_t)4 * M * H3 * 4);
  float* pre_lr = (float*)region1;
  float* S      = (float*)region1;
  float* pre_a  = (float*)region1;
  float* hl_f = (float*)alloc((size_t)M * H2 * 4);
  float* hr_f = (float*)alloc((size_t)M * H2 * 4);
  unsigned short* hl_hi = (unsigned short*)alloc((size_t)M * H2 * 2);
  unsigned short* hl_lo = (unsigned short*)alloc((size_t)M * H2 * 2);
  unsigned short* hr_hi = (unsigned short*)alloc((size_t)M * H2 * 2);
  unsigned short* hr_lo = (unsigned short*)alloc((size_t)M * H2 * 2);
  float* Hc = (float*)alloc((size_t)M * H * 4);
  float* Rc = (float*)alloc((size_t)M * H * 4);
  float* Hm = (float*)alloc((size_t)M * H * 4);
  float* Rm = (float*)alloc((size_t)M * H * 4);
  float* Hp = (float*)alloc((size_t)M * H * 4);
  float* HB = (float*)alloc((size_t)M * H2 * 4);
  float* P = (float*)alloc((size_t)5 * STY * 4);
  unsigned short* agg_hi = (unsigned short*)alloc((size_t)M * H12 * 2);
  unsigned short* agg_lo = (unsigned short*)alloc((size_t)M * H12 * 2);
  float* ar_f = (float*)alloc((size_t)M * H2 * 4);
  unsigned short* ar_hi = (unsigned short*)alloc((size_t)M * H2 * 2);
  unsigned short* ar_lo = (unsigned short*)alloc((size_t)M * H2 * 2);
  float* Arc = (float*)alloc((size_t)M * H * 4);

  // 1. staging
  StageArgs sa{};
  sa.cs[0] = lWhh;  sa.cd[0] = Whh_b;                 sa.cn[0] = 2 * H3 * H;
  sa.cs[1] = rWhh;  sa.cd[1] = Whh_b + 2 * H3 * H;    sa.cn[1] = 2 * H3 * H;
  sa.cs[2] = aWhh;  sa.cd[2] = Whh_b + 4 * H3 * H;    sa.cn[2] = 2 * H3 * H;
  sa.cs[3] = aWih;  sa.cd[3] = aWih_b;                sa.cn[3] = 2 * H3 * H12;
  sa.cs[4] = Wc1;   sa.cd[4] = Wc1_b;                 sa.cn[4] = H * H2;
  sa.cs[5] = Wc2;   sa.cd[5] = Wc2_b;                 sa.cn[5] = H * H2;
  sa.cs[6] = Wm;    sa.cd[6] = Wm_b;                  sa.cn[6] = H * H2;
  sa.cs[7] = Wp;    sa.cd[7] = Wp_b;                  sa.cn[7] = H * H2;
  sa.cs[8] = Wb;    sa.cd[8] = Wb_b;                  sa.cn[8] = H2 * H2;
  sa.idx = inputs; sa.emb = embed; sa.xhi = xhi; sa.xlo = xlo;
  sa.lW = lWih; sa.rW = rWih; sa.wpad = wpad;
  k_stage<<<dim3((2 * H3 * H12 + 255) / 256, 11), dim3(256), 0, stream>>>(sa);

  // 2. input projections for l/r GRUs
  GemmBatch ga{};
  const float* biases[4] = { lbih, lbih + H3, rbih, rbih + H3 };
  for (int u = 0; u < 4; ++u)
    ga.d[u] = GemmDesc{ xhi, xlo, wpad + (size_t)u * H3 * EP, biases[u],
                        pre_lr + (size_t)u * M * H3, H3, EP };
  k_gemm<<<dim3(16, 6, 4), dim3(256), 0, stream>>>(ga);

  // 3. l/r recurrences
  RecArgs r1{};
  r1.whh[0] = Whh_b;               r1.whh[1] = Whh_b + H3 * H;
  r1.whh[2] = Whh_b + 2 * H3 * H;  r1.whh[3] = Whh_b + 3 * H3 * H;
  for (int u = 0; u < 4; ++u) r1.pre[u] = pre_lr + (size_t)u * M * H3;
  r1.outf[0] = r1.outf[1] = hl_f; r1.outf[2] = r1.outf[3] = hr_f;
  r1.bhh[0] = lbhh; r1.bhh[1] = lbhh + H3; r1.bhh[2] = rbhh; r1.bhh[3] = rbhh + H3;
  r1.colOff[0] = 0; r1.colOff[1] = H; r1.colOff[2] = 0; r1.colOff[3] = H;
  r1.dir[0] = 0; r1.dir[1] = 1; r1.dir[2] = 0; r1.dir[3] = 1;
  k_gru<<<dim3(4), dim3(256), 0, stream>>>(r1);

  // 4. hi/lo staging of hl/hr + agg hr-copy
  k_hilo1<<<dim3(1024, 3), dim3(256), 0, stream>>>(hl_f, hr_f, hl_hi, hl_lo,
                                                   hr_hi, hr_lo, agg_hi, agg_lo);

  // 5. projection GEMMs
  GemmBatch gbB{};
  gbB.d[0] = GemmDesc{ hl_hi, hl_lo, Wc1_b, nullptr, Hc, H, H2 };
  gbB.d[1] = GemmDesc{ hr_hi, hr_lo, Wc2_b, nullptr, Rc, H, H2 };
  gbB.d[2] = GemmDesc{ hl_hi, hl_lo, Wm_b, nullptr, Hm, H, H2 };
  gbB.d[3] = GemmDesc{ hr_hi, hr_lo, Wm_b, nullptr, Rm, H, H2 };
  gbB.d[4] = GemmDesc{ hl_hi, hl_lo, Wb_b, nullptr, HB, H2, H2 };
  gbB.d[5] = GemmDesc{ hl_hi, hl_lo, Wp_b, nullptr, Hp, H, H2 };
  k_gemm<<<dim3(16, 4, 6), dim3(256), 0, stream>>>(gbB);

  // 6-8. scores + softmax
  k_score_cmb<<<dim3(M), dim3(256), 0, stream>>>(Hc, Rc, Hm, Rm, HB, hr_f, vc, vmv, S);
  SdArgs sd{};
  sd.Xhi[0] = hl_hi; sd.Wt[0] = Wd;  sd.vt[0] = vd;  sd.So[0] = S + (size_t)2 * STY;
  sd.Xhi[1] = hr_hi; sd.Wt[1] = Wsw; sd.vt[1] = vsv; sd.So[1] = S + (size_t)0 * STY;
  sd.Rf = hr_f;
  k_score_ds<<<dim3(M, 2), dim3(256), 0, stream>>>(sd);
  k_softmax<<<dim3(M), dim3(256), 0, stream>>>(S, P);

  // 9. weighted sums into agg
  k_wsum<<<dim3(32, 5, 4), dim3(256), 0, stream>>>(P, hl_f, hr_f, agg_hi, agg_lo);

  // 10. agg GRU input projection
  GemmBatch gc{};
  gc.d[0] = GemmDesc{ agg_hi, agg_lo, aWih_b, abih, pre_a, H3, H12 };
  gc.d[1] = GemmDesc{ agg_hi, agg_lo, aWih_b + (size_t)H3 * H12, abih + H3,
                      pre_a + (size_t)M * H3, H3, H12 };
  k_gemm<<<dim3(16, 6, 2), dim3(256), 0, stream>>>(gc);

  // 11. agg recurrence
  RecArgs r2{};
  r2.whh[0] = Whh_b + 4 * H3 * H; r2.whh[1] = Whh_b + 5 * H3 * H;
  r2.whh[2] = r2.whh[3] = Whh_b + 4 * H3 * H;
  r2.pre[0] = pre_a; r2.pre[1] = pre_a + (size_t)M * H3;
  r2.pre[2] = r2.pre[3] = pre_a;
  r2.outf[0] = r2.outf[1] = r2.outf[2] = r2.outf[3] = ar_f;
  r2.bhh[0] = abhh; r2.bhh[1] = abhh + H3; r2.bhh[2] = r2.bhh[3] = abhh;
  r2.colOff[0] = 0; r2.colOff[1] = H; r2.colOff[2] = r2.colOff[3] = 0;
  r2.dir[0] = 0; r2.dir[1] = 1; r2.dir[2] = r2.dir[3] = 0;
  k_gru<<<dim3(2), dim3(256), 0, stream>>>(r2);

  // 12-13. ar hi/lo + Arc GEMM
  k_hilo2<<<dim3(1024), dim3(256), 0, stream>>>(ar_f, ar_hi, ar_lo);
  GemmBatch gd{};
  gd.d[0] = GemmDesc{ ar_hi, ar_lo, Wc1_b, nullptr, Arc, H, H2 };
  k_gemm<<<dim3(16, 2, 1), dim3(256), 0, stream>>>(gd);

  // 14. fused tail
  k_tail<<<dim3(4), dim3(256), 0, stream>>>(Hp, hl_f, vp, Wc2, Arc, ar_f, vc, Wpred,
                                            (float*)d_out);
}

// Round 7
// 887.494 us; speedup vs baseline: 1.6160x; 1.1696x over previous
//
#include <hip/hip_runtime.h>

// MANNet forward, MI355X gfx950. Inputs fp32 (+int32 ids), output fp32.
// R7: lgkm-only barriers in k_gru (keep pre-prefetch in flight across steps);
// k_score_ds v3: full-W staging (64KB swizzled LDS), A register-resident,
// X read once, 32 MFMA per 8 X-loads, 3 barriers.

#define DEV static __device__ __forceinline__

// barrier that does NOT drain vmcnt (cross-wave data is LDS-only)
#define BAR_LGKM() __asm__ volatile("s_waitcnt lgkmcnt(0)\ns_barrier" ::: "memory")

typedef __attribute__((ext_vector_type(4))) float f32x4;
typedef __attribute__((ext_vector_type(8))) short s16x8;
typedef __attribute__((ext_vector_type(4))) unsigned int u32x4;

constexpr int T = 256, E = 300, EP = 320, H = 128, H2 = 256, H3 = 384, H12 = 1536;
constexpr int M = 1024;            // B*T
constexpr int STY = 262144;        // 4*T*T elements per score type

DEV float b2f(unsigned short h) { return __uint_as_float(((unsigned)h) << 16); }
DEV unsigned short f2b(float f) {
  unsigned u = __float_as_uint(f);
  u += 0x7fff + ((u >> 16) & 1);            // RNE
  return (unsigned short)(u >> 16);
}
DEV float sigm(float x) { return 1.f / (1.f + __expf(-x)); }
DEV float tanh_f(float x) { float e = __expf(2.f * x); return 1.f - 2.f / (e + 1.f); }

DEV s16x8 ldfrag(const unsigned short* p) {
  u32x4 v = *(const u32x4*)p;
  return __builtin_bit_cast(s16x8, v);
}
DEV f32x4 mfma16(s16x8 a, s16x8 b, f32x4 c) {
  return __builtin_amdgcn_mfma_f32_16x16x32_bf16(a, b, c, 0, 0, 0);
}

// ---------------- fused staging: 9x cvt + embed + padw ----------------

struct StageArgs {
  const float* cs[9]; unsigned short* cd[9]; int cn[9];
  const int* idx; const float* emb; unsigned short* xhi; unsigned short* xlo;
  const float* lW; const float* rW; unsigned short* wpad;
};

__global__ void k_stage(StageArgs sa) {
  int seg = blockIdx.y;
  int i = blockIdx.x * 256 + threadIdx.x;
  if (seg < 9) {
    if (i < sa.cn[seg]) sa.cd[seg][i] = f2b(sa.cs[seg][i]);
    return;
  }
  if (seg == 9) {                       // embedding gather -> padded hi/lo
    if (i >= M * EP) return;
    int m = i / EP, e = i - m * EP;
    int r = sa.idx[m];
    float v = (e < E) ? sa.emb[(size_t)r * E + e] : 0.f;
    unsigned short hi = f2b(v);
    sa.xhi[i] = hi;
    sa.xlo[i] = f2b(v - b2f(hi));
    return;
  }
  // seg 10: Wih (l,r) -> bf16, K padded 300->320
  if (i >= 4 * H3 * EP) return;
  int e = i % EP, n = (i / EP) % H3, uu = i / (EP * H3);
  const float* src = (uu < 2 ? sa.lW : sa.rW) + (size_t)((uu & 1) * H3 + n) * E;
  sa.wpad[i] = (e < E) ? f2b(src[e]) : (unsigned short)0;
}

// ---------------- generic GEMM: C = (Ahi+Alo) @ W^T (+bias), fp32 out ----------

struct GemmDesc {
  const unsigned short* Ahi; const unsigned short* Alo; const unsigned short* W;
  const float* bias; float* Cf; int N; int K;
};
struct GemmBatch { GemmDesc d[8]; };

__global__ __launch_bounds__(256) void k_gemm(GemmBatch gb) {
  GemmDesc g = gb.d[blockIdx.z];
  int nb = blockIdx.y * 64;
  if (nb >= g.N) return;
  int mb = blockIdx.x * 64;
  int lane = threadIdx.x & 63, w = threadIdx.x >> 6, quad = lane >> 4, l16 = lane & 15;
  int K = g.K;
  const unsigned short* Ahp = g.Ahi + (size_t)(mb + w * 16 + l16) * K + quad * 8;
  const unsigned short* Alp = g.Alo + (size_t)(mb + w * 16 + l16) * K + quad * 8;
  const unsigned short* Wp = g.W + (size_t)(nb + l16) * K + quad * 8;
  f32x4 acc[4];
  #pragma unroll
  for (int nt = 0; nt < 4; ++nt) acc[nt] = f32x4{0.f, 0.f, 0.f, 0.f};
  for (int k = 0; k < K; k += 32) {
    s16x8 ah = ldfrag(Ahp + k);
    s16x8 al = ldfrag(Alp + k);
    #pragma unroll
    for (int nt = 0; nt < 4; ++nt) {
      s16x8 b = ldfrag(Wp + (size_t)nt * 16 * K + k);
      acc[nt] = mfma16(ah, b, acc[nt]);
      acc[nt] = mfma16(al, b, acc[nt]);
    }
  }
  int mr0 = mb + w * 16 + quad * 4;
  #pragma unroll
  for (int nt = 0; nt < 4; ++nt) {
    int col = nb + nt * 16 + l16;
    float bv = g.bias ? g.bias[col] : 0.f;
    #pragma unroll
    for (int r = 0; r < 4; ++r)
      g.Cf[(size_t)(mr0 + r) * g.N + col] = acc[nt][r] + bv;
  }
}

// ---------------- GRU recurrence: 1 lgkm-only barrier/step ----------------

struct RecArgs {
  const unsigned short* whh[4];   // staged bf16 (384x128)
  const float* pre[4];
  float* outf[4];
  const float* bhh[4];            // fp32, 384
  int colOff[4];
  int dir[4];
};

__global__ __launch_bounds__(256) void k_gru(RecArgs ra) {
  int u = blockIdx.x;
  __shared__ __align__(16) unsigned short hs[2][16 * 136];
  __shared__ float gh_l[4 * 8 * 96];
  int tid = threadIdx.x, lane = tid & 63, w = tid >> 6;
  int quad = lane >> 4, l16 = lane & 15;
  for (int i = tid; i < 2 * 16 * 136; i += 256) ((unsigned short*)hs)[i] = 0;
  const unsigned short* whh = ra.whh[u];
  s16x8 bq[6][4];
  #pragma unroll
  for (int nt = 0; nt < 6; ++nt) {
    int row = (nt >> 1) * 128 + w * 32 + (nt & 1) * 16 + l16;
    #pragma unroll
    for (int kc = 0; kc < 4; ++kc)
      bq[nt][kc] = ldfrag(whh + (size_t)row * H + kc * 32 + quad * 8);
  }
  const float* bhh = ra.bhh[u];
  const float* pre = ra.pre[u];
  float* outf = ra.outf[u];
  int colOff = ra.colOff[u], dir = ra.dir[u];
  int dd = lane & 31, bp = lane >> 5, b2 = bp + 2;
  int d = w * 32 + dd;
  float bh_r = bhh[d], bh_z = bhh[d + 128], bh_n = bhh[d + 256];
  float hf0 = 0.f, hf1 = 0.f;
  float ob0[8], ob1[8];
  int ghw = w * 8;
  int t0 = dir ? (T - 1) : 0;
  {
    const float* q0 = pre + (size_t)(bp * T + t0) * H3 + d;
    const float* q1 = pre + (size_t)(b2 * T + t0) * H3 + d;
    ob0[0] = q0[0]; ob0[1] = q0[128]; ob0[2] = q0[256];
    ob1[0] = q1[0]; ob1[1] = q1[128]; ob1[2] = q1[256];
  }
  float n_pr0 = ob0[0], n_pz0 = ob0[1], n_pn0 = ob0[2];
  float n_pr1 = ob1[0], n_pz1 = ob1[1], n_pn1 = ob1[2];
  __syncthreads();
  for (int sb = 0; sb < T; sb += 8) {
    #pragma unroll
    for (int ss = 0; ss < 8; ++ss) {
      int s = sb + ss;
      float pr0 = n_pr0, pz0 = n_pz0, pn0 = n_pn0;
      float pr1 = n_pr1, pz1 = n_pz1, pn1 = n_pn1;
      int sn = (s + 1 < T) ? (s + 1) : s;
      int tn = dir ? (T - 1 - sn) : sn;
      const float* f0 = pre + (size_t)(bp * T + tn) * H3 + d;
      const float* f1 = pre + (size_t)(b2 * T + tn) * H3 + d;
      n_pr0 = f0[0]; n_pz0 = f0[128]; n_pn0 = f0[256];
      n_pr1 = f1[0]; n_pz1 = f1[128]; n_pn1 = f1[256];
      const unsigned short* hcur = hs[ss & 1];
      unsigned short* hnxt = hs[(ss & 1) ^ 1];
      s16x8 ah[4];
      #pragma unroll
      for (int kc = 0; kc < 4; ++kc)
        ah[kc] = ldfrag(hcur + l16 * 136 + kc * 32 + quad * 8);
      f32x4 acc[6];
      #pragma unroll
      for (int nt = 0; nt < 6; ++nt) acc[nt] = f32x4{0.f, 0.f, 0.f, 0.f};
      #pragma unroll
      for (int kc = 0; kc < 4; ++kc) {
        #pragma unroll
        for (int nt = 0; nt < 6; ++nt)
          acc[nt] = mfma16(ah[kc], bq[nt][kc], acc[nt]);
      }
      if (quad < 2) {
        #pragma unroll
        for (int nt = 0; nt < 6; ++nt) {
          int gcol = (nt >> 1) * 32 + (nt & 1) * 16 + l16;
          #pragma unroll
          for (int r = 0; r < 4; ++r)
            gh_l[(ghw + quad * 4 + r) * 96 + gcol] = acc[nt][r];
        }
      }
      __asm__ volatile("s_waitcnt lgkmcnt(0)" ::: "memory");
      float r0 = gh_l[(ghw + bp) * 96 + dd]      + gh_l[(ghw + 4 + bp) * 96 + dd];
      float z0 = gh_l[(ghw + bp) * 96 + 32 + dd] + gh_l[(ghw + 4 + bp) * 96 + 32 + dd];
      float nv0 = gh_l[(ghw + bp) * 96 + 64 + dd] + gh_l[(ghw + 4 + bp) * 96 + 64 + dd];
      float r1 = gh_l[(ghw + b2) * 96 + dd]      + gh_l[(ghw + 4 + b2) * 96 + dd];
      float z1 = gh_l[(ghw + b2) * 96 + 32 + dd] + gh_l[(ghw + 4 + b2) * 96 + 32 + dd];
      float nv1 = gh_l[(ghw + b2) * 96 + 64 + dd] + gh_l[(ghw + 4 + b2) * 96 + 64 + dd];
      float rg0 = sigm(pr0 + r0 + bh_r);
      float zg0 = sigm(pz0 + z0 + bh_z);
      float ng0 = tanh_f(pn0 + rg0 * (nv0 + bh_n));
      hf0 = (1.f - zg0) * ng0 + zg0 * hf0;
      unsigned short hi0 = f2b(hf0);
      hnxt[bp * 136 + d] = hi0;
      hnxt[(4 + bp) * 136 + d] = f2b(hf0 - b2f(hi0));
      ob0[ss] = hf0;
      float rg1 = sigm(pr1 + r1 + bh_r);
      float zg1 = sigm(pz1 + z1 + bh_z);
      float ng1 = tanh_f(pn1 + rg1 * (nv1 + bh_n));
      hf1 = (1.f - zg1) * ng1 + zg1 * hf1;
      unsigned short hi1 = f2b(hf1);
      hnxt[b2 * 136 + d] = hi1;
      hnxt[(4 + b2) * 136 + d] = f2b(hf1 - b2f(hi1));
      ob1[ss] = hf1;
      BAR_LGKM();                      // no vmcnt drain: prefetch stays in flight
    }
    #pragma unroll
    for (int qq = 0; qq < 8; ++qq) {
      int sq = sb + qq;
      int tq = dir ? (T - 1 - sq) : sq;
      outf[(size_t)(bp * T + tq) * H2 + colOff + d] = ob0[qq];
      outf[(size_t)(b2 * T + tq) * H2 + colOff + d] = ob1[qq];
    }
  }
}

// ---------------- hi/lo decomposition (post-GRU, parallel) ----------------

__global__ void k_hilo1(const float* __restrict__ hl_f, const float* __restrict__ hr_f,
                        unsigned short* __restrict__ hl_hi, unsigned short* __restrict__ hl_lo,
                        unsigned short* __restrict__ hr_hi, unsigned short* __restrict__ hr_lo,
                        unsigned short* __restrict__ agg_hi, unsigned short* __restrict__ agg_lo) {
  int seg = blockIdx.y;
  int i = blockIdx.x * 256 + threadIdx.x;      // i < M*H2
  if (seg == 0) {
    float v = hl_f[i];
    unsigned short hi = f2b(v);
    hl_hi[i] = hi; hl_lo[i] = f2b(v - b2f(hi));
  } else if (seg == 1) {
    float v = hr_f[i];
    unsigned short hi = f2b(v);
    hr_hi[i] = hi; hr_lo[i] = f2b(v - b2f(hi));
  } else {
    float v = hr_f[i];
    unsigned short hi = f2b(v);
    size_t o = (size_t)(i >> 8) * H12 + (i & 255);
    agg_hi[o] = hi; agg_lo[o] = f2b(v - b2f(hi));
  }
}

__global__ void k_hilo2(const float* __restrict__ src,
                        unsigned short* __restrict__ dhi, unsigned short* __restrict__ dlo) {
  int i = blockIdx.x * 256 + threadIdx.x;
  float v = src[i];
  unsigned short hi = f2b(v);
  dhi[i] = hi; dlo[i] = f2b(v - b2f(hi));
}

// ---------------- cheap scores: co-attention (c), bilinear (b), subtractive (m) ----

__global__ __launch_bounds__(256) void k_score_cmb(
    const float* __restrict__ Hc, const float* __restrict__ Rc,
    const float* __restrict__ Hm, const float* __restrict__ Rm,
    const float* __restrict__ HB, const float* __restrict__ hrf,
    const float* __restrict__ vcf, const float* __restrict__ vmf,
    float* __restrict__ S) {
  int bi = blockIdx.x, b = bi >> 8;
  __shared__ __align__(16) float rc_l[128];
  __shared__ __align__(16) float rm_l[128];
  __shared__ __align__(16) float vc_l[128];
  __shared__ __align__(16) float vm_l[128];
  __shared__ __align__(16) float hr_l[256];
  int tid = threadIdx.x;
  if (tid < 128) {
    rc_l[tid] = Rc[(size_t)bi * 128 + tid];
    rm_l[tid] = Rm[(size_t)bi * 128 + tid];
    vc_l[tid] = vcf[tid];
    vm_l[tid] = vmf[tid];
  }
  hr_l[tid] = hrf[(size_t)bi * 256 + tid];
  __syncthreads();
  int j = tid;
  const float4* hc4 = (const float4*)(Hc + (size_t)(b * 256 + j) * 128);
  const float4* hm4 = (const float4*)(Hm + (size_t)(b * 256 + j) * 128);
  const float4* hb4 = (const float4*)(HB + (size_t)(b * 256 + j) * 256);
  const float4* rc4 = (const float4*)rc_l;
  const float4* rm4 = (const float4*)rm_l;
  const float4* vc4 = (const float4*)vc_l;
  const float4* vm4 = (const float4*)vm_l;
  const float4* hr4 = (const float4*)hr_l;
  float sc = 0.f, sm = 0.f, sb = 0.f;
  #pragma unroll 4
  for (int k = 0; k < 32; ++k) {
    float4 a = hc4[k], c = rc4[k], v = vc4[k];
    sc += v.x * tanh_f(a.x + c.x) + v.y * tanh_f(a.y + c.y)
        + v.z * tanh_f(a.z + c.z) + v.w * tanh_f(a.w + c.w);
    float4 am = hm4[k], cm = rm4[k], vv = vm4[k];
    sm += vv.x * tanh_f(am.x - cm.x) + vv.y * tanh_f(am.y - cm.y)
        + vv.z * tanh_f(am.z - cm.z) + vv.w * tanh_f(am.w - cm.w);
  }
  #pragma unroll 4
  for (int k = 0; k < 64; ++k) {
    float4 p = hb4[k], h = hr4[k];
    sb += p.x * h.x + p.y * h.y + p.z * h.z + p.w * h.w;
  }
  size_t o = (size_t)bi * 256 + j;
  S[(size_t)STY * 1 + o] = sc;   // c
  S[(size_t)STY * 3 + o] = sb;   // b
  S[(size_t)STY * 4 + o] = sm;   // m
}

// ---------------- expensive scores: S[i,j] = v . tanh(W (X_j o R_i)) ------------
// v3: stage ALL 128 rows of (W o R_i) in 64KB LDS (granule-swizzled, no pad),
// A frags register-resident; wave (kh=w&1, jh=w>>1) covers krows kh*64..+64,
// jt jh*8..+8. Per jt: 8 X loads feed 4 independent 8-MFMA chains. After the
// A-frag loads, LDS is reused as sp[2][256] for the cross-wave k-half sum.

struct SdArgs {
  const unsigned short* Xhi[2];
  const float* Rf; const float* Wt[2]; const float* vt[2]; float* So[2];
};

__global__ __launch_bounds__(256, 2) void k_score_ds(SdArgs a) {
  int which = blockIdx.y;
  const unsigned short* Xhi = a.Xhi[which];
  const float* W = a.Wt[which];
  const float* v = a.vt[which];
  float* Sout = a.So[which];
  int bi = blockIdx.x, b = bi >> 8;
  __shared__ __align__(16) unsigned char smem[65536];
  unsigned short* w_lds = (unsigned short*)smem;       // 128 rows x 256 (swizzled)
  float* sp = (float*)smem;                            // aliases after A-load
  int tid = threadIdx.x, lane = tid & 63, w = tid >> 6, quad = lane >> 4, l16 = lane & 15;
  int kh = w & 1, jh = w >> 1;
  // stage: thread owns d4 = tid&63 forever; rows kl = it*4 + (tid>>6)
  int d4 = tid & 63, rhi = tid >> 6;
  float4 h4 = ((const float4*)(a.Rf + (size_t)bi * 256))[d4];
  #pragma unroll
  for (int it = 0; it < 32; ++it) {
    int kl = it * 4 + rhi;
    float4 w4 = ((const float4*)(W + (size_t)kl * 256))[d4];
    unsigned long long pk =
        (unsigned long long)f2b(w4.x * h4.x)
      | ((unsigned long long)f2b(w4.y * h4.y) << 16)
      | ((unsigned long long)f2b(w4.z * h4.z) << 32)
      | ((unsigned long long)f2b(w4.w * h4.w) << 48);
    int gphys = ((d4 >> 1) + kl) & 31;                 // 16B-granule swizzle
    *(unsigned long long*)(w_lds + (size_t)kl * 256 + gphys * 8 + (d4 & 1) * 4) = pk;
  }
  BAR_LGKM();
  // A frags: 4 chunks x 8 kc, register resident
  s16x8 afr[4][8];
  #pragma unroll
  for (int c = 0; c < 4; ++c) {
    int krow = kh * 64 + c * 16 + l16;
    #pragma unroll
    for (int kc = 0; kc < 8; ++kc) {
      int gp = (kc * 4 + quad + krow) & 31;
      afr[c][kc] = ldfrag(w_lds + (size_t)krow * 256 + gp * 8);
    }
  }
  float vv[4][4];
  #pragma unroll
  for (int c = 0; c < 4; ++c)
    #pragma unroll
    for (int r = 0; r < 4; ++r) vv[c][r] = v[kh * 64 + c * 16 + quad * 4 + r];
  BAR_LGKM();                                          // all A reads done -> reuse LDS
  #pragma unroll
  for (int jj = 0; jj < 8; ++jj) {
    int jt = jh * 8 + jj;
    const unsigned short* Xp = Xhi + (size_t)(b * 256 + jt * 16 + l16) * 256 + quad * 8;
    s16x8 bf[8];
    #pragma unroll
    for (int kc = 0; kc < 8; ++kc) bf[kc] = ldfrag(Xp + kc * 32);
    f32x4 acc[4];
    #pragma unroll
    for (int c = 0; c < 4; ++c) acc[c] = f32x4{0.f, 0.f, 0.f, 0.f};
    #pragma unroll
    for (int kc = 0; kc < 8; ++kc) {
      #pragma unroll
      for (int c = 0; c < 4; ++c) acc[c] = mfma16(afr[c][kc], bf[kc], acc[c]);
    }
    float s = 0.f;
    #pragma unroll
    for (int c = 0; c < 4; ++c)
      #pragma unroll
      for (int r = 0; r < 4; ++r) s += tanh_f(acc[c][r]) * vv[c][r];
    s += __shfl_xor(s, 16);
    s += __shfl_xor(s, 32);                            // sum over quads (k-segments)
    if (lane < 16) sp[kh * 256 + jt * 16 + l16] = s;
  }
  BAR_LGKM();
  Sout[(size_t)bi * 256 + tid] = sp[tid] + sp[256 + tid];
}

// ---------------- softmax over j for all 5 score types (fp32 out) --------------

__global__ __launch_bounds__(256) void k_softmax(const float* __restrict__ S,
                                                 float* __restrict__ P) {
  int bi = blockIdx.x, tid = threadIdx.x;
  __shared__ float red[4];
  for (int type = 0; type < 5; ++type) {
    size_t o = (size_t)type * STY + (size_t)bi * 256 + tid;
    float x = S[o];
    float m = x;
    for (int dl = 32; dl; dl >>= 1) m = fmaxf(m, __shfl_xor(m, dl));
    if ((tid & 63) == 0) red[tid >> 6] = m;
    __syncthreads();
    m = fmaxf(fmaxf(red[0], red[1]), fmaxf(red[2], red[3]));
    __syncthreads();
    float e = __expf(x - m);
    float sum = e;
    for (int dl = 32; dl; dl >>= 1) sum += __shfl_xor(sum, dl);
    if ((tid & 63) == 0) red[tid >> 6] = sum;
    __syncthreads();
    sum = red[0] + red[1] + red[2] + red[3];
    P[o] = e / sum;
    __syncthreads();
  }
}

// ---------------- 5 weighted sums into agg (hi/lo bf16 out) ----------------

__global__ __launch_bounds__(256) void k_wsum(const float* __restrict__ P,
    const float* __restrict__ hl_f, const float* __restrict__ hr_f,
    unsigned short* __restrict__ ahi, unsigned short* __restrict__ alo) {
  int it = blockIdx.x, type = blockIdx.y, b = blockIdx.z;
  __shared__ float p_l[8][256];
  int tid = threadIdx.x;
  for (int ii = 0; ii < 8; ++ii)
    p_l[ii][tid] = P[((size_t)(type * 4 + b) * 256 + it * 8 + ii) * 256 + tid];
  __syncthreads();
  const float* src = (type == 0 ? hr_f : hl_f) + (size_t)b * 256 * 256;
  float acc[8] = {0.f, 0.f, 0.f, 0.f, 0.f, 0.f, 0.f, 0.f};
  for (int j = 0; j < 256; ++j) {
    float hv = src[(size_t)j * 256 + tid];
    #pragma unroll
    for (int ii = 0; ii < 8; ++ii) acc[ii] += p_l[ii][j] * hv;
  }
  int off = 256 * (1 + type);      // agg: [hr | pts | ptc | ptd | ptb | ptm]
  #pragma unroll
  for (int ii = 0; ii < 8; ++ii) {
    float vv = acc[ii];
    unsigned short hi = f2b(vv);
    size_t o = (size_t)(b * 256 + it * 8 + ii) * H12 + off + tid;
    ahi[o] = hi;
    alo[o] = f2b(vv - b2f(hi));
  }
}

// ---------------- fused tail: pooling over hl + final attention + predict -------

__global__ __launch_bounds__(256) void k_tail(const float* __restrict__ Hp,
    const float* __restrict__ hl_f, const float* __restrict__ vpf,
    const float* __restrict__ Wc2f, const float* __restrict__ Arc,
    const float* __restrict__ ar_f, const float* __restrict__ vcf,
    const float* __restrict__ Wpredf, float* __restrict__ out) {
  int b = blockIdx.x, tid = threadIdx.x;
  __shared__ float vl[128], wl[256], rvec[256], rlcl[128], red[4];
  if (tid < 128) vl[tid] = vpf[tid];
  __syncthreads();
  const float* hp = Hp + (size_t)(b * 256 + tid) * 128;
  float s = 0.f;
  for (int k = 0; k < 128; ++k) s += vl[k] * tanh_f(hp[k]);
  float m = s;
  for (int dl = 32; dl; dl >>= 1) m = fmaxf(m, __shfl_xor(m, dl));
  if ((tid & 63) == 0) red[tid >> 6] = m;
  __syncthreads();
  m = fmaxf(fmaxf(red[0], red[1]), fmaxf(red[2], red[3]));
  __syncthreads();
  float e = __expf(s - m);
  float sum = e;
  for (int dl = 32; dl; dl >>= 1) sum += __shfl_xor(sum, dl);
  if ((tid & 63) == 0) red[tid >> 6] = sum;
  __syncthreads();
  sum = red[0] + red[1] + red[2] + red[3];
  wl[tid] = e / sum;
  __syncthreads();
  float acc = 0.f;
  for (int t = 0; t < 256; ++t) acc += wl[t] * hl_f[(size_t)(b * 256 + t) * 256 + tid];
  rvec[tid] = acc;
  __syncthreads();
  if (tid < 128) {
    float a2 = 0.f;
    const float* wr = Wc2f + (size_t)tid * 256;
    for (int dk = 0; dk < 256; ++dk) a2 += rvec[dk] * wr[dk];
    rlcl[tid] = a2;
    vl[tid] = vcf[tid];
  }
  __syncthreads();
  const float* ap = Arc + (size_t)(b * 256 + tid) * 128;
  float s2 = 0.f;
  for (int k = 0; k < 128; ++k) s2 += vl[k] * (ap[k] + rlcl[k]);
  m = s2;
  for (int dl = 32; dl; dl >>= 1) m = fmaxf(m, __shfl_xor(m, dl));
  if ((tid & 63) == 0) red[tid >> 6] = m;
  __syncthreads();
  m = fmaxf(fmaxf(red[0], red[1]), fmaxf(red[2], red[3]));
  __syncthreads();
  float e2 = __expf(s2 - m);
  float sum2 = e2;
  for (int dl = 32; dl; dl >>= 1) sum2 += __shfl_xor(sum2, dl);
  if ((tid & 63) == 0) red[tid >> 6] = sum2;
  __syncthreads();
  sum2 = red[0] + red[1] + red[2] + red[3];
  wl[tid] = e2 / sum2;
  __syncthreads();
  float acc2 = 0.f;
  for (int t = 0; t < 256; ++t) acc2 += wl[t] * ar_f[(size_t)(b * 256 + t) * 256 + tid];
  rvec[tid] = acc2;
  __syncthreads();
  if (tid < 2) {
    float o = 0.f;
    const float* wp = Wpredf + (size_t)tid * 256;
    for (int dk = 0; dk < 256; ++dk) o += rvec[dk] * wp[dk];
    out[b * 2 + tid] = sigm(o);
  }
}

// ---------------- host ----------------

extern "C" void kernel_launch(void* const* d_in, const int* in_sizes, int n_in,
                              void* d_out, int out_size, void* d_ws, size_t ws_size,
                              hipStream_t stream) {
  (void)in_sizes; (void)n_in; (void)out_size; (void)ws_size;
  const int* inputs = (const int*)d_in[0];
  const float* embed = (const float*)d_in[1];
  const float* lWih = (const float*)d_in[2];
  const float* lWhh = (const float*)d_in[3];
  const float* lbih = (const float*)d_in[4];
  const float* lbhh = (const float*)d_in[5];
  const float* rWih = (const float*)d_in[6];
  const float* rWhh = (const float*)d_in[7];
  const float* rbih = (const float*)d_in[8];
  const float* rbhh = (const float*)d_in[9];
  const float* aWih = (const float*)d_in[10];
  const float* aWhh = (const float*)d_in[11];
  const float* abih = (const float*)d_in[12];
  const float* abhh = (const float*)d_in[13];
  const float* Wc1 = (const float*)d_in[14];
  const float* Wc2 = (const float*)d_in[15];
  const float* vc  = (const float*)d_in[16];
  const float* Wb  = (const float*)d_in[17];
  const float* Wd  = (const float*)d_in[18];
  const float* vd  = (const float*)d_in[19];
  const float* Wm  = (const float*)d_in[20];
  const float* vmv = (const float*)d_in[21];
  const float* Wsw = (const float*)d_in[22];
  const float* vsv = (const float*)d_in[23];
  const float* Wp  = (const float*)d_in[24];
  const float* vp  = (const float*)d_in[25];
  const float* Wpred = (const float*)d_in[26];

  char* ws = (char*)d_ws;
  size_t off = 0;
  auto alloc = [&](size_t bytes) -> void* {
    void* p = ws + off;
    off += (bytes + 255) & ~(size_t)255;
    return p;
  };
  unsigned short* xhi = (unsigned short*)alloc((size_t)M * EP * 2);
  unsigned short* xlo = (unsigned short*)alloc((size_t)M * EP * 2);
  unsigned short* wpad = (unsigned short*)alloc((size_t)4 * H3 * EP * 2);
  unsigned short* Whh_b = (unsigned short*)alloc((size_t)6 * H3 * H * 2);
  unsigned short* aWih_b = (unsigned short*)alloc((size_t)2 * H3 * H12 * 2);
  unsigned short* Wc1_b = (unsigned short*)alloc((size_t)H * H2 * 2);
  unsigned short* Wc2_b = (unsigned short*)alloc((size_t)H * H2 * 2);
  unsigned short* Wm_b  = (unsigned short*)alloc((size_t)H * H2 * 2);
  unsigned short* Wp_b  = (unsigned short*)alloc((size_t)H * H2 * 2);
  unsigned short* Wb_b  = (unsigned short*)alloc((size_t)H2 * H2 * 2);
  char* region1 = (char*)alloc((size_t)4 * M * H3 * 4);
  float* pre_lr = (float*)region1;
  float* S      = (float*)region1;
  float* pre_a  = (float*)region1;
  float* hl_f = (float*)alloc((size_t)M * H2 * 4);
  float* hr_f = (float*)alloc((size_t)M * H2 * 4);
  unsigned short* hl_hi = (unsigned short*)alloc((size_t)M * H2 * 2);
  unsigned short* hl_lo = (unsigned short*)alloc((size_t)M * H2 * 2);
  unsigned short* hr_hi = (unsigned short*)alloc((size_t)M * H2 * 2);
  unsigned short* hr_lo = (unsigned short*)alloc((size_t)M * H2 * 2);
  float* Hc = (float*)alloc((size_t)M * H * 4);
  float* Rc = (float*)alloc((size_t)M * H * 4);
  float* Hm = (float*)alloc((size_t)M * H * 4);
  float* Rm = (float*)alloc((size_t)M * H * 4);
  float* Hp = (float*)alloc((size_t)M * H * 4);
  float* HB = (float*)alloc((size_t)M * H2 * 4);
  float* P = (float*)alloc((size_t)5 * STY * 4);
  unsigned short* agg_hi = (unsigned short*)alloc((size_t)M * H12 * 2);
  unsigned short* agg_lo = (unsigned short*)alloc((size_t)M * H12 * 2);
  float* ar_f = (float*)alloc((size_t)M * H2 * 4);
  unsigned short* ar_hi = (unsigned short*)alloc((size_t)M * H2 * 2);
  unsigned short* ar_lo = (unsigned short*)alloc((size_t)M * H2 * 2);
  float* Arc = (float*)alloc((size_t)M * H * 4);

  // 1. staging
  StageArgs sa{};
  sa.cs[0] = lWhh;  sa.cd[0] = Whh_b;                 sa.cn[0] = 2 * H3 * H;
  sa.cs[1] = rWhh;  sa.cd[1] = Whh_b + 2 * H3 * H;    sa.cn[1] = 2 * H3 * H;
  sa.cs[2] = aWhh;  sa.cd[2] = Whh_b + 4 * H3 * H;    sa.cn[2] = 2 * H3 * H;
  sa.cs[3] = aWih;  sa.cd[3] = aWih_b;                sa.cn[3] = 2 * H3 * H12;
  sa.cs[4] = Wc1;   sa.cd[4] = Wc1_b;                 sa.cn[4] = H * H2;
  sa.cs[5] = Wc2;   sa.cd[5] = Wc2_b;                 sa.cn[5] = H * H2;
  sa.cs[6] = Wm;    sa.cd[6] = Wm_b;                  sa.cn[6] = H * H2;
  sa.cs[7] = Wp;    sa.cd[7] = Wp_b;                  sa.cn[7] = H * H2;
  sa.cs[8] = Wb;    sa.cd[8] = Wb_b;                  sa.cn[8] = H2 * H2;
  sa.idx = inputs; sa.emb = embed; sa.xhi = xhi; sa.xlo = xlo;
  sa.lW = lWih; sa.rW = rWih; sa.wpad = wpad;
  k_stage<<<dim3((2 * H3 * H12 + 255) / 256, 11), dim3(256), 0, stream>>>(sa);

  // 2. input projections for l/r GRUs
  GemmBatch ga{};
  const float* biases[4] = { lbih, lbih + H3, rbih, rbih + H3 };
  for (int u = 0; u < 4; ++u)
    ga.d[u] = GemmDesc{ xhi, xlo, wpad + (size_t)u * H3 * EP, biases[u],
                        pre_lr + (size_t)u * M * H3, H3, EP };
  k_gemm<<<dim3(16, 6, 4), dim3(256), 0, stream>>>(ga);

  // 3. l/r recurrences
  RecArgs r1{};
  r1.whh[0] = Whh_b;               r1.whh[1] = Whh_b + H3 * H;
  r1.whh[2] = Whh_b + 2 * H3 * H;  r1.whh[3] = Whh_b + 3 * H3 * H;
  for (int u = 0; u < 4; ++u) r1.pre[u] = pre_lr + (size_t)u * M * H3;
  r1.outf[0] = r1.outf[1] = hl_f; r1.outf[2] = r1.outf[3] = hr_f;
  r1.bhh[0] = lbhh; r1.bhh[1] = lbhh + H3; r1.bhh[2] = rbhh; r1.bhh[3] = rbhh + H3;
  r1.colOff[0] = 0; r1.colOff[1] = H; r1.colOff[2] = 0; r1.colOff[3] = H;
  r1.dir[0] = 0; r1.dir[1] = 1; r1.dir[2] = 0; r1.dir[3] = 1;
  k_gru<<<dim3(4), dim3(256), 0, stream>>>(r1);

  // 4. hi/lo staging of hl/hr + agg hr-copy
  k_hilo1<<<dim3(1024, 3), dim3(256), 0, stream>>>(hl_f, hr_f, hl_hi, hl_lo,
                                                   hr_hi, hr_lo, agg_hi, agg_lo);

  // 5. projection GEMMs
  GemmBatch gbB{};
  gbB.d[0] = GemmDesc{ hl_hi, hl_lo, Wc1_b, nullptr, Hc, H, H2 };
  gbB.d[1] = GemmDesc{ hr_hi, hr_lo, Wc2_b, nullptr, Rc, H, H2 };
  gbB.d[2] = GemmDesc{ hl_hi, hl_lo, Wm_b, nullptr, Hm, H, H2 };
  gbB.d[3] = GemmDesc{ hr_hi, hr_lo, Wm_b, nullptr, Rm, H, H2 };
  gbB.d[4] = GemmDesc{ hl_hi, hl_lo, Wb_b, nullptr, HB, H2, H2 };
  gbB.d[5] = GemmDesc{ hl_hi, hl_lo, Wp_b, nullptr, Hp, H, H2 };
  k_gemm<<<dim3(16, 4, 6), dim3(256), 0, stream>>>(gbB);

  // 6-8. scores + softmax
  k_score_cmb<<<dim3(M), dim3(256), 0, stream>>>(Hc, Rc, Hm, Rm, HB, hr_f, vc, vmv, S);
  SdArgs sd{};
  sd.Xhi[0] = hl_hi; sd.Wt[0] = Wd;  sd.vt[0] = vd;  sd.So[0] = S + (size_t)2 * STY;
  sd.Xhi[1] = hr_hi; sd.Wt[1] = Wsw; sd.vt[1] = vsv; sd.So[1] = S + (size_t)0 * STY;
  sd.Rf = hr_f;
  k_score_ds<<<dim3(M, 2), dim3(256), 0, stream>>>(sd);
  k_softmax<<<dim3(M), dim3(256), 0, stream>>>(S, P);

  // 9. weighted sums into agg
  k_wsum<<<dim3(32, 5, 4), dim3(256), 0, stream>>>(P, hl_f, hr_f, agg_hi, agg_lo);

  // 10. agg GRU input projection
  GemmBatch gc{};
  gc.d[0] = GemmDesc{ agg_hi, agg_lo, aWih_b, abih, pre_a, H3, H12 };
  gc.d[1] = GemmDesc{ agg_hi, agg_lo, aWih_b + (size_t)H3 * H12, abih + H3,
                      pre_a + (size_t)M * H3, H3, H12 };
  k_gemm<<<dim3(16, 6, 2), dim3(256), 0, stream>>>(gc);

  // 11. agg recurrence
  RecArgs r2{};
  r2.whh[0] = Whh_b + 4 * H3 * H; r2.whh[1] = Whh_b + 5 * H3 * H;
  r2.whh[2] = r2.whh[3] = Whh_b + 4 * H3 * H;
  r2.pre[0] = pre_a; r2.pre[1] = pre_a + (size_t)M * H3;
  r2.pre[2] = r2.pre[3] = pre_a;
  r2.outf[0] = r2.outf[1] = r2.outf[2] = r2.outf[3] = ar_f;
  r2.bhh[0] = abhh; r2.bhh[1] = abhh + H3; r2.bhh[2] = r2.bhh[3] = abhh;
  r2.colOff[0] = 0; r2.colOff[1] = H; r2.colOff[2] = r2.colOff[3] = 0;
  r2.dir[0] = 0; r2.dir[1] = 1; r2.dir[2] = r2.dir[3] = 0;
  k_gru<<<dim3(2), dim3(256), 0, stream>>>(r2);

  // 12-13. ar hi/lo + Arc GEMM
  k_hilo2<<<dim3(1024), dim3(256), 0, stream>>>(ar_f, ar_hi, ar_lo);
  GemmBatch gd{};
  gd.d[0] = GemmDesc{ ar_hi, ar_lo, Wc1_b, nullptr, Arc, H, H2 };
  k_gemm<<<dim3(16, 2, 1), dim3(256), 0, stream>>>(gd);

  // 14. fused tail
  k_tail<<<dim3(4), dim3(256), 0, stream>>>(Hp, hl_f, vp, Wc2, Arc, ar_f, vc, Wpred,
                                            (float*)d_out);
}